// Round 1
// baseline (333.451 us; speedup 1.0000x reference)
//
#include <hip/hip_runtime.h>
#include <math.h>

#define NB 4
#define SEQ 1024
#define DM 1024
#define NH 16
#define HS 64

typedef __attribute__((ext_vector_type(8))) short short8;
typedef __attribute__((ext_vector_type(4))) float floatx4;

#define MFMA(a, b, c) __builtin_amdgcn_mfma_f32_16x16x32_bf16((a), (b), (c), 0, 0, 0)

static __device__ __forceinline__ unsigned short f2bf(float f) {
  unsigned int u = __float_as_uint(f);
  u += 0x7FFFu + ((u >> 16) & 1u);   // RNE
  return (unsigned short)(u >> 16);
}
static __device__ __forceinline__ float bf2f(unsigned short s) {
  return __uint_as_float(((unsigned int)s) << 16);
}

// C[b,h,t,e] = sum_k x[m][k] * W[h][k][e],  m = b*SEQ+t. Output bf16 [B*H][T][HS].
__global__ __launch_bounds__(256) void qkv_gemm(
    const float* __restrict__ x,        // [4096][1024]
    const float* __restrict__ W,        // [NH][DM][HS]
    unsigned short* __restrict__ outp)  // [NB*NH*SEQ*HS]
{
  __shared__ __align__(16) short As[64 * 72];
  __shared__ __align__(16) short Bs[64 * 72];
  const int tid = threadIdx.x;
  const int bm = blockIdx.x;
  const int h = blockIdx.y;
  const int lane = tid & 63, wave = tid >> 6;
  const int quad = lane >> 4, l16 = lane & 15;
  const int wr = wave >> 1, wc = wave & 1;
  const float* Wh = W + (size_t)h * DM * HS;
  const floatx4 fzero = {0.f, 0.f, 0.f, 0.f};

  floatx4 acc[2][2];
#pragma unroll
  for (int i = 0; i < 2; i++)
#pragma unroll
    for (int j = 0; j < 2; j++) acc[i][j] = fzero;

  for (int k0 = 0; k0 < DM; k0 += 64) {
    __syncthreads();
    // Stage A: x tile [64 rows][64 k], f32 -> bf16, row-major in LDS.
#pragma unroll
    for (int i = 0; i < 4; i++) {
      int p = tid + i * 256;
      int row = p >> 4, c4 = (p & 15) << 2;
      float4 v = *(const float4*)(x + (size_t)(bm * 64 + row) * DM + k0 + c4);
      short* d = &As[row * 72 + c4];
      d[0] = (short)f2bf(v.x); d[1] = (short)f2bf(v.y);
      d[2] = (short)f2bf(v.z); d[3] = (short)f2bf(v.w);
    }
    // Stage B transposed: W[h][k][e] -> Bs[e][k].
#pragma unroll
    for (int i = 0; i < 4; i++) {
      int p = tid + i * 256;
      int row = p >> 4, c4 = (p & 15) << 2;
      float4 v = *(const float4*)(Wh + (size_t)(k0 + row) * HS + c4);
      Bs[(c4 + 0) * 72 + row] = (short)f2bf(v.x);
      Bs[(c4 + 1) * 72 + row] = (short)f2bf(v.y);
      Bs[(c4 + 2) * 72 + row] = (short)f2bf(v.z);
      Bs[(c4 + 3) * 72 + row] = (short)f2bf(v.w);
    }
    __syncthreads();

    short8 af[2][2], bfr[2][2];
#pragma unroll
    for (int ti = 0; ti < 2; ti++)
#pragma unroll
      for (int kh = 0; kh < 2; kh++)
        af[ti][kh] = *(const short8*)&As[(wr * 32 + ti * 16 + l16) * 72 + kh * 32 + quad * 8];
#pragma unroll
    for (int tj = 0; tj < 2; tj++)
#pragma unroll
      for (int kh = 0; kh < 2; kh++)
        bfr[tj][kh] = *(const short8*)&Bs[(wc * 32 + tj * 16 + l16) * 72 + kh * 32 + quad * 8];
#pragma unroll
    for (int ti = 0; ti < 2; ti++)
#pragma unroll
      for (int tj = 0; tj < 2; tj++) {
        acc[ti][tj] = MFMA(af[ti][0], bfr[tj][0], acc[ti][tj]);
        acc[ti][tj] = MFMA(af[ti][1], bfr[tj][1], acc[ti][tj]);
      }
  }

#pragma unroll
  for (int ti = 0; ti < 2; ti++)
#pragma unroll
    for (int tj = 0; tj < 2; tj++)
#pragma unroll
      for (int r = 0; r < 4; r++) {
        int m = bm * 64 + wr * 32 + ti * 16 + quad * 4 + r;
        int e = wc * 32 + tj * 16 + l16;
        int bb = m >> 10, t = m & (SEQ - 1);
        outp[((size_t)(bb * NH + h) * SEQ + t) * HS + e] = f2bf(acc[ti][tj][r]);
      }
}

// Flash-style causal attention for one (b, h, 64-row Q tile).
__global__ __launch_bounds__(256) void attn_kernel(
    const unsigned short* __restrict__ q,   // [B*H][T][HS] bf16
    const unsigned short* __restrict__ k,
    const unsigned short* __restrict__ v,
    unsigned short* __restrict__ o)         // [B*T][NH*HS] bf16
{
  __shared__ __align__(16) short Qs[64 * 72];
  __shared__ __align__(16) short Ks[64 * 72];
  __shared__ __align__(16) short Vt[64 * 72];   // transposed: Vt[e][s]
  __shared__ __align__(16) short Ps[64 * 72];
  const int tid = threadIdx.x;
  const int qt = blockIdx.x, h = blockIdx.y, b = blockIdx.z;
  const int lane = tid & 63, wave = tid >> 6;
  const int quad = lane >> 4, l16 = lane & 15;
  const size_t bh = (size_t)(b * NH + h) * SEQ * HS;
  const unsigned short* qp = q + bh + (size_t)qt * 64 * HS;
  const floatx4 fzero = {0.f, 0.f, 0.f, 0.f};

  // Load Q tile, fold in 1/sqrt(HS) = 0.125 (exact).
#pragma unroll
  for (int i = 0; i < 16; i++) {
    int p = tid + i * 256;
    int row = p >> 6, col = p & 63;
    Qs[row * 72 + col] = (short)f2bf(bf2f(qp[p]) * 0.125f);
  }

  float m_[4], l_[4];
  floatx4 O[4];
#pragma unroll
  for (int r = 0; r < 4; r++) { m_[r] = -INFINITY; l_[r] = 0.f; }
#pragma unroll
  for (int tj = 0; tj < 4; tj++) O[tj] = fzero;

  for (int kt = 0; kt <= qt; kt++) {
    const unsigned short* kp = k + bh + (size_t)kt * 64 * HS;
    const unsigned short* vp = v + bh + (size_t)kt * 64 * HS;
    __syncthreads();   // protect Ks/Vt from previous iteration's readers
#pragma unroll
    for (int i = 0; i < 2; i++) {
      int p = tid + i * 256;
      int row = p >> 3, c8 = (p & 7) << 3;
      *(short8*)&Ks[row * 72 + c8] = *(const short8*)(kp + row * HS + c8);
    }
#pragma unroll
    for (int i = 0; i < 16; i++) {
      int p = tid + i * 256;
      int s = p >> 6, e = p & 63;
      Vt[e * 72 + s] = (short)vp[p];
    }
    __syncthreads();

    // S = Q K^T for this wave's 16 rows x 64 cols.
    short8 a0 = *(const short8*)&Qs[(wave * 16 + l16) * 72 + quad * 8];
    short8 a1 = *(const short8*)&Qs[(wave * 16 + l16) * 72 + 32 + quad * 8];
    floatx4 S[4];
#pragma unroll
    for (int tj = 0; tj < 4; tj++) {
      short8 b0 = *(const short8*)&Ks[(tj * 16 + l16) * 72 + quad * 8];
      short8 b1 = *(const short8*)&Ks[(tj * 16 + l16) * 72 + 32 + quad * 8];
      floatx4 s = fzero;
      s = MFMA(a0, b0, s);
      s = MFMA(a1, b1, s);
      S[tj] = s;
    }
    if (kt == qt) {   // causal mask only on the diagonal tile
#pragma unroll
      for (int tj = 0; tj < 4; tj++) {
        int col = tj * 16 + l16;
#pragma unroll
        for (int r = 0; r < 4; r++) {
          int row = wave * 16 + quad * 4 + r;
          if (col > row) S[tj][r] = -INFINITY;
        }
      }
    }
    // Online softmax. Row owners: lanes of one quad share 4 rows.
    float nm[4], alpha[4], rsum[4];
#pragma unroll
    for (int r = 0; r < 4; r++) {
      float mx = fmaxf(fmaxf(S[0][r], S[1][r]), fmaxf(S[2][r], S[3][r]));
#pragma unroll
      for (int off = 1; off < 16; off <<= 1)
        mx = fmaxf(mx, __shfl_xor(mx, off, 16));
      nm[r] = fmaxf(m_[r], mx);
      alpha[r] = __expf(m_[r] - nm[r]);   // first iter: exp(-inf)=0
      rsum[r] = 0.f;
    }
#pragma unroll
    for (int tj = 0; tj < 4; tj++)
#pragma unroll
      for (int r = 0; r < 4; r++) {
        float pv = __expf(S[tj][r] - nm[r]);
        S[tj][r] = pv;
        rsum[r] += pv;
      }
#pragma unroll
    for (int r = 0; r < 4; r++) {
#pragma unroll
      for (int off = 1; off < 16; off <<= 1)
        rsum[r] += __shfl_xor(rsum[r], off, 16);
      l_[r] = l_[r] * alpha[r] + rsum[r];
      m_[r] = nm[r];
    }
    // P: C-layout -> LDS (wave-private rows, no cross-wave barrier needed).
#pragma unroll
    for (int tj = 0; tj < 4; tj++)
#pragma unroll
      for (int r = 0; r < 4; r++)
        Ps[(wave * 16 + quad * 4 + r) * 72 + tj * 16 + l16] = (short)f2bf(S[tj][r]);
#pragma unroll
    for (int tj = 0; tj < 4; tj++)
#pragma unroll
      for (int r = 0; r < 4; r++) O[tj][r] *= alpha[r];

    // O += P V
    short8 pa0 = *(const short8*)&Ps[(wave * 16 + l16) * 72 + quad * 8];
    short8 pa1 = *(const short8*)&Ps[(wave * 16 + l16) * 72 + 32 + quad * 8];
#pragma unroll
    for (int tj = 0; tj < 4; tj++) {
      short8 b0 = *(const short8*)&Vt[(tj * 16 + l16) * 72 + quad * 8];
      short8 b1 = *(const short8*)&Vt[(tj * 16 + l16) * 72 + 32 + quad * 8];
      O[tj] = MFMA(pa0, b0, O[tj]);
      O[tj] = MFMA(pa1, b1, O[tj]);
    }
  }

#pragma unroll
  for (int r = 0; r < 4; r++) {
    float inv = 1.0f / l_[r];
    int t = qt * 64 + wave * 16 + quad * 4 + r;
#pragma unroll
    for (int tj = 0; tj < 4; tj++) {
      int e = tj * 16 + l16;
      o[((size_t)(b * SEQ + t)) * (NH * HS) + h * HS + e] = f2bf(O[tj][r] * inv);
    }
  }
}

// out[m][n] = sum_k A[m][k] * Wo[k][n] + bo[n], A bf16, Wo f32, out f32.
__global__ __launch_bounds__(256) void out_gemm(
    const unsigned short* __restrict__ A,   // [4096][1024] bf16
    const float* __restrict__ Wo,           // [1024][1024]
    const float* __restrict__ bo,           // [1024]
    float* __restrict__ out)                // [4096][1024]
{
  __shared__ __align__(16) short As[64 * 72];
  __shared__ __align__(16) short Bs[64 * 72];
  const int tid = threadIdx.x;
  const int bm = blockIdx.x, bn = blockIdx.y;
  const int lane = tid & 63, wave = tid >> 6;
  const int quad = lane >> 4, l16 = lane & 15;
  const int wr = wave >> 1, wc = wave & 1;
  const floatx4 fzero = {0.f, 0.f, 0.f, 0.f};

  floatx4 acc[2][2];
#pragma unroll
  for (int i = 0; i < 2; i++)
#pragma unroll
    for (int j = 0; j < 2; j++) acc[i][j] = fzero;

  for (int k0 = 0; k0 < DM; k0 += 64) {
    __syncthreads();
#pragma unroll
    for (int i = 0; i < 2; i++) {
      int p = tid + i * 256;
      int row = p >> 3, c8 = (p & 7) << 3;
      *(short8*)&As[row * 72 + c8] =
          *(const short8*)(A + (size_t)(bm * 64 + row) * DM + k0 + c8);
    }
#pragma unroll
    for (int i = 0; i < 4; i++) {
      int p = tid + i * 256;
      int row = p >> 4, c4 = (p & 15) << 2;
      float4 v = *(const float4*)(Wo + (size_t)(k0 + row) * DM + bn * 64 + c4);
      Bs[(c4 + 0) * 72 + row] = (short)f2bf(v.x);
      Bs[(c4 + 1) * 72 + row] = (short)f2bf(v.y);
      Bs[(c4 + 2) * 72 + row] = (short)f2bf(v.z);
      Bs[(c4 + 3) * 72 + row] = (short)f2bf(v.w);
    }
    __syncthreads();

    short8 af[2][2], bfr[2][2];
#pragma unroll
    for (int ti = 0; ti < 2; ti++)
#pragma unroll
      for (int kh = 0; kh < 2; kh++)
        af[ti][kh] = *(const short8*)&As[(wr * 32 + ti * 16 + l16) * 72 + kh * 32 + quad * 8];
#pragma unroll
    for (int tj = 0; tj < 2; tj++)
#pragma unroll
      for (int kh = 0; kh < 2; kh++)
        bfr[tj][kh] = *(const short8*)&Bs[(wc * 32 + tj * 16 + l16) * 72 + kh * 32 + quad * 8];
#pragma unroll
    for (int ti = 0; ti < 2; ti++)
#pragma unroll
      for (int tj = 0; tj < 2; tj++) {
        acc[ti][tj] = MFMA(af[ti][0], bfr[tj][0], acc[ti][tj]);
        acc[ti][tj] = MFMA(af[ti][1], bfr[tj][1], acc[ti][tj]);
      }
  }

#pragma unroll
  for (int ti = 0; ti < 2; ti++)
#pragma unroll
    for (int tj = 0; tj < 2; tj++)
#pragma unroll
      for (int r = 0; r < 4; r++) {
        int m = bm * 64 + wr * 32 + ti * 16 + quad * 4 + r;
        int n = bn * 64 + wc * 32 + tj * 16 + l16;
        out[(size_t)m * DM + n] = acc[ti][tj][r] + bo[n];
      }
}

extern "C" void kernel_launch(void* const* d_in, const int* in_sizes, int n_in,
                              void* d_out, int out_size, void* d_ws, size_t ws_size,
                              hipStream_t stream) {
  const float* x  = (const float*)d_in[0];
  const float* Wq = (const float*)d_in[1];
  const float* Wk = (const float*)d_in[2];
  const float* Wv = (const float*)d_in[3];
  const float* Wo = (const float*)d_in[4];
  const float* bo = (const float*)d_in[5];
  float* out = (float*)d_out;

  const size_t nqkv = (size_t)NB * NH * SEQ * HS;   // 4M elements
  unsigned short* qws = (unsigned short*)d_ws;
  unsigned short* kws = qws + nqkv;
  unsigned short* vws = kws + nqkv;
  unsigned short* aws = vws + nqkv;   // attention output, [B*T][NH*HS]

  dim3 blk(256);
  qkv_gemm<<<dim3(64, NH), blk, 0, stream>>>(x, Wq, qws);
  qkv_gemm<<<dim3(64, NH), blk, 0, stream>>>(x, Wk, kws);
  qkv_gemm<<<dim3(64, NH), blk, 0, stream>>>(x, Wv, vws);
  attn_kernel<<<dim3(SEQ / 64, NH, NB), blk, 0, stream>>>(qws, kws, vws, aws);
  out_gemm<<<dim3(64, DM / 64), blk, 0, stream>>>(aws, Wo, bo, out);
}

// Round 2
// 224.101 us; speedup vs baseline: 1.4880x; 1.4880x over previous
//
#include <hip/hip_runtime.h>
#include <math.h>

#define NB 4
#define SEQ 1024
#define DM 1024
#define NH 16
#define HS 64

typedef __attribute__((ext_vector_type(8))) short short8;
typedef __attribute__((ext_vector_type(4))) short short4v;
typedef __attribute__((ext_vector_type(4))) float floatx4;

#define MFMA(a, b, c) __builtin_amdgcn_mfma_f32_16x16x32_bf16((a), (b), (c), 0, 0, 0)

static __device__ __forceinline__ unsigned short f2bf(float f) {
  unsigned int u = __float_as_uint(f);
  u += 0x7FFFu + ((u >> 16) & 1u);   // RNE
  return (unsigned short)(u >> 16);
}

// ---------- P1: cast x (f32 -> bf16), 4M elements ----------
__global__ __launch_bounds__(256) void cast_x(
    const float* __restrict__ x, unsigned short* __restrict__ xb) {
  int base = blockIdx.x * 1024;
#pragma unroll
  for (int i = 0; i < 4; i++) {
    int idx4 = base + threadIdx.x + i * 256;
    float4 v = *(const float4*)(x + (size_t)idx4 * 4);
    short4v o;
    o[0] = (short)f2bf(v.x); o[1] = (short)f2bf(v.y);
    o[2] = (short)f2bf(v.z); o[3] = (short)f2bf(v.w);
    *(short4v*)(xb + (size_t)idx4 * 4) = o;
  }
}

// ---------- P2: transpose+cast weights ----------
// y=0..2: Wq/Wk/Wv [NH][DM][HS] -> Wt [NH*HS rows][DM]  (row = h*64+e)
// y=3:    Wo [DM][DM] -> Wot [n][k]
__global__ __launch_bounds__(256) void prep_w(
    const float* __restrict__ Wq, const float* __restrict__ Wk,
    const float* __restrict__ Wv, const float* __restrict__ Wo,
    unsigned short* __restrict__ Wtq, unsigned short* __restrict__ Wtk,
    unsigned short* __restrict__ Wtv, unsigned short* __restrict__ Wot) {
  __shared__ __align__(16) short Ts[64 * 72];
  const int tid = threadIdx.x;
  const int mat = blockIdx.y;
  const float* src;
  unsigned short* dst;
  int r0, c0;   // tile origin in source: rows = contraction dim, cols = out-row dim
  if (mat < 3) {
    src = (mat == 0) ? Wq : (mat == 1) ? Wk : Wv;
    dst = (mat == 0) ? Wtq : (mat == 1) ? Wtk : Wtv;
    int h = blockIdx.x >> 4;
    int d0 = (blockIdx.x & 15) * 64;
    src += (size_t)(h * DM + d0) * HS;   // tile [64 d][64 e], row stride HS
    dst += (size_t)(h * HS) * DM + d0;   // out rows e, cols d
    r0 = HS;  c0 = DM;                   // src row stride, dst row stride
  } else {
    src = Wo; dst = Wot;
    int k0 = (blockIdx.x >> 4) * 64;
    int n0 = (blockIdx.x & 15) * 64;
    src += (size_t)k0 * DM + n0;         // tile [64 k][64 n], row stride DM
    dst += (size_t)n0 * DM + k0;
    r0 = DM;  c0 = DM;
  }
#pragma unroll
  for (int i = 0; i < 4; i++) {
    int p = tid + i * 256;
    int row = p >> 4, c4 = (p & 15) << 2;
    float4 v = *(const float4*)(src + (size_t)row * r0 + c4);
    Ts[(c4 + 0) * 72 + row] = (short)f2bf(v.x);
    Ts[(c4 + 1) * 72 + row] = (short)f2bf(v.y);
    Ts[(c4 + 2) * 72 + row] = (short)f2bf(v.z);
    Ts[(c4 + 3) * 72 + row] = (short)f2bf(v.w);
  }
  __syncthreads();
#pragma unroll
  for (int i = 0; i < 2; i++) {
    int p = tid + i * 256;
    int row = p >> 3, c8 = (p & 7) << 3;
    *(short8*)(dst + (size_t)row * c0 + c8) = *(const short8*)&Ts[row * 72 + c8];
  }
}

// ---------- G1: fused qkv GEMM ----------
// q,k out: [B,H,T,HS]; v out transposed: [B,H,HS,T]
__global__ __launch_bounds__(256) void qkv_fused(
    const unsigned short* __restrict__ xb,    // [4096][1024]
    const unsigned short* __restrict__ Wtq,   // [1024][1024]
    const unsigned short* __restrict__ Wtk,
    const unsigned short* __restrict__ Wtv,
    unsigned short* __restrict__ qo,
    unsigned short* __restrict__ ko,
    unsigned short* __restrict__ vo) {
  __shared__ __align__(16) short As[64 * 72];
  __shared__ __align__(16) short Bq[64 * 72];
  __shared__ __align__(16) short Bk[64 * 72];
  __shared__ __align__(16) short Bv[64 * 72];
  const int tid = threadIdx.x;
  const int bm = blockIdx.x, h = blockIdx.y;
  const int lane = tid & 63, wave = tid >> 6;
  const int quad = lane >> 4, l16 = lane & 15;
  const int wr = wave >> 1, wc = wave & 1;
  const floatx4 fzero = {0.f, 0.f, 0.f, 0.f};

  floatx4 aq[2][2], ak[2][2], av[2][2];
#pragma unroll
  for (int i = 0; i < 2; i++)
#pragma unroll
    for (int j = 0; j < 2; j++) { aq[i][j] = fzero; ak[i][j] = fzero; av[i][j] = fzero; }

  const int srow = tid >> 3, sc8 = (tid & 7) << 3;       // first 512-elem chunk
  const int srow2 = srow + 32;

  for (int k0 = 0; k0 < DM; k0 += 64) {
    __syncthreads();
    // A tile: xb rows m, cols k
    *(short8*)&As[srow * 72 + sc8] =
        *(const short8*)(xb + (size_t)(bm * 64 + srow) * DM + k0 + sc8);
    *(short8*)&As[srow2 * 72 + sc8] =
        *(const short8*)(xb + (size_t)(bm * 64 + srow2) * DM + k0 + sc8);
    // B tiles: Wt rows h*64+e, cols k
    const size_t wb1 = (size_t)(h * HS + srow) * DM + k0 + sc8;
    const size_t wb2 = (size_t)(h * HS + srow2) * DM + k0 + sc8;
    *(short8*)&Bq[srow * 72 + sc8]  = *(const short8*)(Wtq + wb1);
    *(short8*)&Bq[srow2 * 72 + sc8] = *(const short8*)(Wtq + wb2);
    *(short8*)&Bk[srow * 72 + sc8]  = *(const short8*)(Wtk + wb1);
    *(short8*)&Bk[srow2 * 72 + sc8] = *(const short8*)(Wtk + wb2);
    *(short8*)&Bv[srow * 72 + sc8]  = *(const short8*)(Wtv + wb1);
    *(short8*)&Bv[srow2 * 72 + sc8] = *(const short8*)(Wtv + wb2);
    __syncthreads();

    short8 af[2][2];
#pragma unroll
    for (int ti = 0; ti < 2; ti++)
#pragma unroll
      for (int kh = 0; kh < 2; kh++)
        af[ti][kh] = *(const short8*)&As[(wr * 32 + ti * 16 + l16) * 72 + kh * 32 + quad * 8];

    short8 bf[2][2];
#pragma unroll
    for (int tj = 0; tj < 2; tj++)
#pragma unroll
      for (int kh = 0; kh < 2; kh++)
        bf[tj][kh] = *(const short8*)&Bq[(wc * 32 + tj * 16 + l16) * 72 + kh * 32 + quad * 8];
#pragma unroll
    for (int ti = 0; ti < 2; ti++)
#pragma unroll
      for (int tj = 0; tj < 2; tj++) {
        aq[ti][tj] = MFMA(af[ti][0], bf[tj][0], aq[ti][tj]);
        aq[ti][tj] = MFMA(af[ti][1], bf[tj][1], aq[ti][tj]);
      }
#pragma unroll
    for (int tj = 0; tj < 2; tj++)
#pragma unroll
      for (int kh = 0; kh < 2; kh++)
        bf[tj][kh] = *(const short8*)&Bk[(wc * 32 + tj * 16 + l16) * 72 + kh * 32 + quad * 8];
#pragma unroll
    for (int ti = 0; ti < 2; ti++)
#pragma unroll
      for (int tj = 0; tj < 2; tj++) {
        ak[ti][tj] = MFMA(af[ti][0], bf[tj][0], ak[ti][tj]);
        ak[ti][tj] = MFMA(af[ti][1], bf[tj][1], ak[ti][tj]);
      }
#pragma unroll
    for (int tj = 0; tj < 2; tj++)
#pragma unroll
      for (int kh = 0; kh < 2; kh++)
        bf[tj][kh] = *(const short8*)&Bv[(wc * 32 + tj * 16 + l16) * 72 + kh * 32 + quad * 8];
#pragma unroll
    for (int ti = 0; ti < 2; ti++)
#pragma unroll
      for (int tj = 0; tj < 2; tj++) {
        av[ti][tj] = MFMA(af[ti][0], bf[tj][0], av[ti][tj]);
        av[ti][tj] = MFMA(af[ti][1], bf[tj][1], av[ti][tj]);
      }
  }

  const int b = bm >> 4;
  const int tbase = (bm & 15) * 64 + wr * 32 + quad * 4;
#pragma unroll
  for (int ti = 0; ti < 2; ti++)
#pragma unroll
    for (int tj = 0; tj < 2; tj++) {
      int t0 = tbase + ti * 16;
      int e = wc * 32 + tj * 16 + l16;
      size_t qk_base = ((size_t)(b * NH + h) * SEQ) * HS + e;
#pragma unroll
      for (int r = 0; r < 4; r++) {
        qo[qk_base + (size_t)(t0 + r) * HS] = f2bf(aq[ti][tj][r]);
        ko[qk_base + (size_t)(t0 + r) * HS] = f2bf(ak[ti][tj][r]);
      }
      short4v pv;
#pragma unroll
      for (int r = 0; r < 4; r++) pv[r] = (short)f2bf(av[ti][tj][r]);
      *(short4v*)&vo[((size_t)(b * NH + h) * HS + e) * SEQ + t0] = pv;
    }
}

// ---------- G2: flash attention ----------
__global__ __launch_bounds__(256) void attn_kernel(
    const unsigned short* __restrict__ q,   // [B,H,T,HS]
    const unsigned short* __restrict__ k,   // [B,H,T,HS]
    const unsigned short* __restrict__ v,   // [B,H,HS,T]  (pre-transposed)
    unsigned short* __restrict__ o)         // [B,T,H*HS]
{
  __shared__ __align__(16) short Qs[64 * 72];
  __shared__ __align__(16) short Ks[64 * 72];
  __shared__ __align__(16) short Vt[64 * 72];
  __shared__ __align__(16) short Ps[64 * 72];
  const int tid = threadIdx.x;
  const int qt = blockIdx.x, h = blockIdx.y, b = blockIdx.z;
  const int lane = tid & 63, wave = tid >> 6;
  const int quad = lane >> 4, l16 = lane & 15;
  const size_t bh = (size_t)(b * NH + h) * SEQ * HS;
  const floatx4 fzero = {0.f, 0.f, 0.f, 0.f};
  const float c = 0.125f * 1.44269504089f;   // scale * log2(e)

  const int srow = tid >> 3, sc8 = (tid & 7) << 3;
  const int srow2 = srow + 32;

  // Stage Q once (raw; scale folded into exp2 args).
  const unsigned short* qp = q + bh + (size_t)qt * 64 * HS;
  *(short8*)&Qs[srow * 72 + sc8]  = *(const short8*)(qp + srow * HS + sc8);
  *(short8*)&Qs[srow2 * 72 + sc8] = *(const short8*)(qp + srow2 * HS + sc8);
  __syncthreads();
  const short8 qa0 = *(const short8*)&Qs[(wave * 16 + l16) * 72 + quad * 8];
  const short8 qa1 = *(const short8*)&Qs[(wave * 16 + l16) * 72 + 32 + quad * 8];

  float m_[4], l_[4];
  floatx4 O[4];
#pragma unroll
  for (int r = 0; r < 4; r++) { m_[r] = -INFINITY; l_[r] = 0.f; }
#pragma unroll
  for (int tj = 0; tj < 4; tj++) O[tj] = fzero;

  for (int kt = 0; kt <= qt; kt++) {
    const unsigned short* kp = k + bh + (size_t)kt * 64 * HS;
    const unsigned short* vp = v + bh + (size_t)kt * 64;   // rows e, stride SEQ
    __syncthreads();
    *(short8*)&Ks[srow * 72 + sc8]  = *(const short8*)(kp + srow * HS + sc8);
    *(short8*)&Ks[srow2 * 72 + sc8] = *(const short8*)(kp + srow2 * HS + sc8);
    *(short8*)&Vt[srow * 72 + sc8]  = *(const short8*)(vp + (size_t)srow * SEQ + sc8);
    *(short8*)&Vt[srow2 * 72 + sc8] = *(const short8*)(vp + (size_t)srow2 * SEQ + sc8);
    __syncthreads();

    floatx4 S[4];
#pragma unroll
    for (int tj = 0; tj < 4; tj++) {
      short8 b0 = *(const short8*)&Ks[(tj * 16 + l16) * 72 + quad * 8];
      short8 b1 = *(const short8*)&Ks[(tj * 16 + l16) * 72 + 32 + quad * 8];
      floatx4 s = fzero;
      s = MFMA(qa0, b0, s);
      s = MFMA(qa1, b1, s);
      S[tj] = s;
    }
    if (kt == qt) {
#pragma unroll
      for (int tj = 0; tj < 4; tj++) {
        int col = tj * 16 + l16;
#pragma unroll
        for (int r = 0; r < 4; r++) {
          int row = wave * 16 + quad * 4 + r;
          if (col > row) S[tj][r] = -INFINITY;
        }
      }
    }
    float nm[4], alpha[4], rsum[4];
#pragma unroll
    for (int r = 0; r < 4; r++) {
      float mx = fmaxf(fmaxf(S[0][r], S[1][r]), fmaxf(S[2][r], S[3][r]));
#pragma unroll
      for (int off = 1; off < 16; off <<= 1)
        mx = fmaxf(mx, __shfl_xor(mx, off, 16));
      nm[r] = fmaxf(m_[r], mx);
      alpha[r] = __builtin_amdgcn_exp2f((m_[r] - nm[r]) * c);
      rsum[r] = 0.f;
    }
#pragma unroll
    for (int tj = 0; tj < 4; tj++)
#pragma unroll
      for (int r = 0; r < 4; r++) {
        float pv = __builtin_amdgcn_exp2f((S[tj][r] - nm[r]) * c);
        S[tj][r] = pv;
        rsum[r] += pv;
      }
#pragma unroll
    for (int r = 0; r < 4; r++) {
#pragma unroll
      for (int off = 1; off < 16; off <<= 1)
        rsum[r] += __shfl_xor(rsum[r], off, 16);
      l_[r] = l_[r] * alpha[r] + rsum[r];
      m_[r] = nm[r];
    }
    // P: C-layout -> LDS (wave-private rows).
#pragma unroll
    for (int tj = 0; tj < 4; tj++)
#pragma unroll
      for (int r = 0; r < 4; r++)
        Ps[(wave * 16 + quad * 4 + r) * 72 + tj * 16 + l16] = (short)f2bf(S[tj][r]);
#pragma unroll
    for (int tj = 0; tj < 4; tj++)
#pragma unroll
      for (int r = 0; r < 4; r++) O[tj][r] *= alpha[r];

    short8 pa0 = *(const short8*)&Ps[(wave * 16 + l16) * 72 + quad * 8];
    short8 pa1 = *(const short8*)&Ps[(wave * 16 + l16) * 72 + 32 + quad * 8];
#pragma unroll
    for (int tj = 0; tj < 4; tj++) {
      short8 b0 = *(const short8*)&Vt[(tj * 16 + l16) * 72 + quad * 8];
      short8 b1 = *(const short8*)&Vt[(tj * 16 + l16) * 72 + 32 + quad * 8];
      O[tj] = MFMA(pa0, b0, O[tj]);
      O[tj] = MFMA(pa1, b1, O[tj]);
    }
  }

#pragma unroll
  for (int r = 0; r < 4; r++) {
    float inv = 1.0f / l_[r];
    int t = qt * 64 + wave * 16 + quad * 4 + r;
#pragma unroll
    for (int tj = 0; tj < 4; tj++) {
      int e = tj * 16 + l16;
      o[((size_t)(b * SEQ + t)) * (NH * HS) + h * HS + e] = f2bf(O[tj][r] * inv);
    }
  }
}

// ---------- G3: output projection ----------
__global__ __launch_bounds__(256) void out_gemm(
    const unsigned short* __restrict__ A,    // [4096][1024] bf16
    const unsigned short* __restrict__ Bt,   // Wot [n][k] bf16
    const float* __restrict__ bo,
    float* __restrict__ out) {
  __shared__ __align__(16) short As[64 * 72];
  __shared__ __align__(16) short Bs[64 * 72];
  const int tid = threadIdx.x;
  const int bm = blockIdx.x, bn = blockIdx.y;
  const int lane = tid & 63, wave = tid >> 6;
  const int quad = lane >> 4, l16 = lane & 15;
  const int wr = wave >> 1, wc = wave & 1;
  const floatx4 fzero = {0.f, 0.f, 0.f, 0.f};

  floatx4 acc[2][2];
#pragma unroll
  for (int i = 0; i < 2; i++)
#pragma unroll
    for (int j = 0; j < 2; j++) acc[i][j] = fzero;

  const int srow = tid >> 3, sc8 = (tid & 7) << 3;
  const int srow2 = srow + 32;

  for (int k0 = 0; k0 < DM; k0 += 64) {
    __syncthreads();
    *(short8*)&As[srow * 72 + sc8] =
        *(const short8*)(A + (size_t)(bm * 64 + srow) * DM + k0 + sc8);
    *(short8*)&As[srow2 * 72 + sc8] =
        *(const short8*)(A + (size_t)(bm * 64 + srow2) * DM + k0 + sc8);
    *(short8*)&Bs[srow * 72 + sc8] =
        *(const short8*)(Bt + (size_t)(bn * 64 + srow) * DM + k0 + sc8);
    *(short8*)&Bs[srow2 * 72 + sc8] =
        *(const short8*)(Bt + (size_t)(bn * 64 + srow2) * DM + k0 + sc8);
    __syncthreads();

    short8 af[2][2], bf[2][2];
#pragma unroll
    for (int ti = 0; ti < 2; ti++)
#pragma unroll
      for (int kh = 0; kh < 2; kh++)
        af[ti][kh] = *(const short8*)&As[(wr * 32 + ti * 16 + l16) * 72 + kh * 32 + quad * 8];
#pragma unroll
    for (int tj = 0; tj < 2; tj++)
#pragma unroll
      for (int kh = 0; kh < 2; kh++)
        bf[tj][kh] = *(const short8*)&Bs[(wc * 32 + tj * 16 + l16) * 72 + kh * 32 + quad * 8];
#pragma unroll
    for (int ti = 0; ti < 2; ti++)
#pragma unroll
      for (int tj = 0; tj < 2; tj++) {
        acc[ti][tj] = MFMA(af[ti][0], bf[tj][0], acc[ti][tj]);
        acc[ti][tj] = MFMA(af[ti][1], bf[tj][1], acc[ti][tj]);
      }
  }

#pragma unroll
  for (int ti = 0; ti < 2; ti++)
#pragma unroll
    for (int tj = 0; tj < 2; tj++)
#pragma unroll
      for (int r = 0; r < 4; r++) {
        int m = bm * 64 + wr * 32 + ti * 16 + quad * 4 + r;
        int n = bn * 64 + wc * 32 + tj * 16 + l16;
        out[(size_t)m * DM + n] = acc[ti][tj][r] + bo[n];
      }
}

extern "C" void kernel_launch(void* const* d_in, const int* in_sizes, int n_in,
                              void* d_out, int out_size, void* d_ws, size_t ws_size,
                              hipStream_t stream) {
  const float* x  = (const float*)d_in[0];
  const float* Wq = (const float*)d_in[1];
  const float* Wk = (const float*)d_in[2];
  const float* Wv = (const float*)d_in[3];
  const float* Wo = (const float*)d_in[4];
  const float* bo = (const float*)d_in[5];
  float* out = (float*)d_out;

  const size_t nx = (size_t)NB * SEQ * DM;          // 4M
  const size_t nw = (size_t)DM * DM;                // 1M
  unsigned short* xb  = (unsigned short*)d_ws;
  unsigned short* wtq = xb + nx;
  unsigned short* wtk = wtq + nw;
  unsigned short* wtv = wtk + nw;
  unsigned short* wot = wtv + nw;
  unsigned short* qws = wot + nw;
  unsigned short* kws = qws + nx;
  unsigned short* vws = kws + nx;
  unsigned short* aws = vws + nx;

  dim3 blk(256);
  cast_x<<<dim3(1024), blk, 0, stream>>>(x, xb);
  prep_w<<<dim3(256, 4), blk, 0, stream>>>(Wq, Wk, Wv, Wo, wtq, wtk, wtv, wot);
  qkv_fused<<<dim3(64, NH), blk, 0, stream>>>(xb, wtq, wtk, wtv, qws, kws, vws);
  attn_kernel<<<dim3(SEQ / 64, NH, NB), blk, 0, stream>>>(qws, kws, vws, aws);
  out_gemm<<<dim3(64, DM / 64), blk, 0, stream>>>(aws, wot, bo, out);
}

// Round 3
// 223.597 us; speedup vs baseline: 1.4913x; 1.0023x over previous
//
#include <hip/hip_runtime.h>
#include <math.h>

#define NB 4
#define SEQ 1024
#define DM 1024
#define NH 16
#define HS 64

typedef __attribute__((ext_vector_type(8))) short short8;
typedef __attribute__((ext_vector_type(4))) short short4v;
typedef __attribute__((ext_vector_type(4))) float floatx4;

#define MFMA(a, b, c) __builtin_amdgcn_mfma_f32_16x16x32_bf16((a), (b), (c), 0, 0, 0)

static __device__ __forceinline__ unsigned short f2bf(float f) {
  unsigned int u = __float_as_uint(f);
  u += 0x7FFFu + ((u >> 16) & 1u);   // RNE
  return (unsigned short)(u >> 16);
}

// 16B async global->LDS. LDS dest must be wave-uniform base + lane*16.
static __device__ __forceinline__ void g2l(const unsigned short* g, short* l) {
  __builtin_amdgcn_global_load_lds(
      (const __attribute__((address_space(1))) void*)g,
      (__attribute__((address_space(3))) void*)l, 16, 0, 0);
}

// ---------- P1: cast x (f32 -> bf16) ----------
__global__ __launch_bounds__(256) void cast_x(
    const float* __restrict__ x, unsigned short* __restrict__ xb) {
  int base = blockIdx.x * 1024;
#pragma unroll
  for (int i = 0; i < 4; i++) {
    int idx4 = base + threadIdx.x + i * 256;
    float4 v = *(const float4*)(x + (size_t)idx4 * 4);
    short4v o;
    o[0] = (short)f2bf(v.x); o[1] = (short)f2bf(v.y);
    o[2] = (short)f2bf(v.z); o[3] = (short)f2bf(v.w);
    *(short4v*)(xb + (size_t)idx4 * 4) = o;
  }
}

// ---------- P2: transpose+cast weights ----------
__global__ __launch_bounds__(256) void prep_w(
    const float* __restrict__ Wq, const float* __restrict__ Wk,
    const float* __restrict__ Wv, const float* __restrict__ Wo,
    unsigned short* __restrict__ Wtq, unsigned short* __restrict__ Wtk,
    unsigned short* __restrict__ Wtv, unsigned short* __restrict__ Wot) {
  __shared__ __align__(16) short Ts[64 * 72];
  const int tid = threadIdx.x;
  const int mat = blockIdx.y;
  const float* src;
  unsigned short* dst;
  int r0, c0;
  if (mat < 3) {
    src = (mat == 0) ? Wq : (mat == 1) ? Wk : Wv;
    dst = (mat == 0) ? Wtq : (mat == 1) ? Wtk : Wtv;
    int h = blockIdx.x >> 4;
    int d0 = (blockIdx.x & 15) * 64;
    src += (size_t)(h * DM + d0) * HS;
    dst += (size_t)(h * HS) * DM + d0;
    r0 = HS;  c0 = DM;
  } else {
    src = Wo; dst = Wot;
    int k0 = (blockIdx.x >> 4) * 64;
    int n0 = (blockIdx.x & 15) * 64;
    src += (size_t)k0 * DM + n0;
    dst += (size_t)n0 * DM + k0;
    r0 = DM;  c0 = DM;
  }
#pragma unroll
  for (int i = 0; i < 4; i++) {
    int p = tid + i * 256;
    int row = p >> 4, c4 = (p & 15) << 2;
    float4 v = *(const float4*)(src + (size_t)row * r0 + c4);
    Ts[(c4 + 0) * 72 + row] = (short)f2bf(v.x);
    Ts[(c4 + 1) * 72 + row] = (short)f2bf(v.y);
    Ts[(c4 + 2) * 72 + row] = (short)f2bf(v.z);
    Ts[(c4 + 3) * 72 + row] = (short)f2bf(v.w);
  }
  __syncthreads();
#pragma unroll
  for (int i = 0; i < 2; i++) {
    int p = tid + i * 256;
    int row = p >> 3, c8 = (p & 7) << 3;
    *(short8*)(dst + (size_t)row * c0 + c8) = *(const short8*)&Ts[row * 72 + c8];
  }
}

// ---------- G1: fused QKV as one 4096x3072x1024 GEMM, 128x128 tiles ----------
__global__ __launch_bounds__(256) void qkv_gemm128(
    const unsigned short* __restrict__ xb,    // [4096][1024]
    const unsigned short* __restrict__ Wcat,  // [3072][1024] = Wtq|Wtk|Wtv
    unsigned short* __restrict__ qo,          // [B,H,T,HS]
    unsigned short* __restrict__ ko,          // [B,H,T,HS]
    unsigned short* __restrict__ vo) {        // [B,H,HS,T]
  __shared__ __align__(16) short As[128 * 64];
  __shared__ __align__(16) short Bs[128 * 64];
  const int tid = threadIdx.x;
  const int bm = blockIdx.x, bn = blockIdx.y;
  const int lane = tid & 63, wave = tid >> 6;
  const int quad = lane >> 4, l16 = lane & 15;
  const int wr = wave >> 1, wc = wave & 1;
  const floatx4 fzero = {0.f, 0.f, 0.f, 0.f};

  floatx4 acc[4][4];
#pragma unroll
  for (int i = 0; i < 4; i++)
#pragma unroll
    for (int j = 0; j < 4; j++) acc[i][j] = fzero;

  const int srow = tid >> 3, scol = (tid & 7) << 3;
  const unsigned short* Ag = xb + (size_t)(bm * 128 + srow) * DM + scol;
  const unsigned short* Bg = Wcat + (size_t)(bn * 128 + srow) * DM + scol;
  short* Ad = As + tid * 8;
  short* Bd = Bs + tid * 8;

  for (int k0 = 0; k0 < DM; k0 += 64) {
    __syncthreads();
#pragma unroll
    for (int i = 0; i < 4; i++) g2l(Ag + (size_t)i * 32 * DM + k0, Ad + i * 2048);
#pragma unroll
    for (int i = 0; i < 4; i++) g2l(Bg + (size_t)i * 32 * DM + k0, Bd + i * 2048);
    __syncthreads();

    short8 af[4][2], bf[4][2];
#pragma unroll
    for (int ti = 0; ti < 4; ti++)
#pragma unroll
      for (int kh = 0; kh < 2; kh++)
        af[ti][kh] = *(const short8*)&As[(wr * 64 + ti * 16 + l16) * 64 + kh * 32 + quad * 8];
#pragma unroll
    for (int tj = 0; tj < 4; tj++)
#pragma unroll
      for (int kh = 0; kh < 2; kh++)
        bf[tj][kh] = *(const short8*)&Bs[(wc * 64 + tj * 16 + l16) * 64 + kh * 32 + quad * 8];
#pragma unroll
    for (int ti = 0; ti < 4; ti++)
#pragma unroll
      for (int tj = 0; tj < 4; tj++) {
        acc[ti][tj] = MFMA(af[ti][0], bf[tj][0], acc[ti][tj]);
        acc[ti][tj] = MFMA(af[ti][1], bf[tj][1], acc[ti][tj]);
      }
  }

  const int mat = bn >> 3;                    // 8 n-tiles per matrix
  const int mbase = bm * 128 + wr * 64 + quad * 4;
  const int nn0 = (bn & 7) * 128 + wc * 64;
  if (mat < 2) {
    unsigned short* dst = (mat == 0) ? qo : ko;
#pragma unroll
    for (int ti = 0; ti < 4; ti++)
#pragma unroll
      for (int tj = 0; tj < 4; tj++) {
        int ecol = nn0 + tj * 16 + l16;
        int h = ecol >> 6, e = ecol & 63;
#pragma unroll
        for (int r = 0; r < 4; r++) {
          int m = mbase + ti * 16 + r;
          int b = m >> 10, t = m & (SEQ - 1);
          dst[((size_t)(b * NH + h) * SEQ + t) * HS + e] = f2bf(acc[ti][tj][r]);
        }
      }
  } else {
#pragma unroll
    for (int ti = 0; ti < 4; ti++)
#pragma unroll
      for (int tj = 0; tj < 4; tj++) {
        int ecol = nn0 + tj * 16 + l16;
        int h = ecol >> 6, e = ecol & 63;
        int m0 = mbase + ti * 16;
        int b = m0 >> 10, t0 = m0 & (SEQ - 1);
        short4v pv;
#pragma unroll
        for (int r = 0; r < 4; r++) pv[r] = (short)f2bf(acc[ti][tj][r]);
        *(short4v*)&vo[((size_t)(b * NH + h) * HS + e) * SEQ + t0] = pv;
      }
  }
}

// ---------- G2: flash attention, 128-row Q tile / block ----------
__global__ __launch_bounds__(256) void attn_kernel(
    const unsigned short* __restrict__ q,   // [B,H,T,HS]
    const unsigned short* __restrict__ k,   // [B,H,T,HS]
    const unsigned short* __restrict__ v,   // [B,H,HS,T]
    unsigned short* __restrict__ o)         // [B,T,H*HS]
{
  __shared__ __align__(16) short Qs[128 * 64];
  __shared__ __align__(16) short Ks[64 * 64];
  __shared__ __align__(16) short Vt[64 * 64];
  __shared__ __align__(16) short Ps[128 * 64];
  const int tid = threadIdx.x;
  const int qt = blockIdx.x, h = blockIdx.y, b = blockIdx.z;
  const int lane = tid & 63, wave = tid >> 6;
  const int quad = lane >> 4, l16 = lane & 15;
  const size_t bh = (size_t)(b * NH + h) * SEQ * HS;
  const unsigned short* qp = q + bh + (size_t)qt * 128 * HS;
  const unsigned short* kbase = k + bh;
  const unsigned short* vbase = v + (size_t)(b * NH + h) * HS * SEQ;
  const floatx4 fzero = {0.f, 0.f, 0.f, 0.f};
  const float c = 0.125f * 1.44269504089f;   // scale * log2(e)
  const int srow = tid >> 3, scol = (tid & 7) << 3;

  // Stage Q once; hold fragments in registers.
#pragma unroll
  for (int i = 0; i < 4; i++)
    g2l(qp + (size_t)(srow + i * 32) * HS + scol, Qs + tid * 8 + i * 2048);
  __syncthreads();
  short8 qa[2][2];
#pragma unroll
  for (int ih = 0; ih < 2; ih++)
#pragma unroll
    for (int kh = 0; kh < 2; kh++)
      qa[ih][kh] = *(const short8*)&Qs[(wave * 32 + ih * 16 + l16) * 64 + kh * 32 + quad * 8];

  const int rowbase = qt * 128 + wave * 32;
  float m_[2][4], l_[2][4];
  floatx4 O[2][4];
#pragma unroll
  for (int ih = 0; ih < 2; ih++)
#pragma unroll
    for (int r = 0; r < 4; r++) { m_[ih][r] = -INFINITY; l_[ih][r] = 0.f; }
#pragma unroll
  for (int ih = 0; ih < 2; ih++)
#pragma unroll
    for (int tj = 0; tj < 4; tj++) O[ih][tj] = fzero;

  const int ktmax = 2 * qt + 1;
  for (int kt = 0; kt <= ktmax; kt++) {
    __syncthreads();
    const unsigned short* kp = kbase + (size_t)kt * 64 * HS;
#pragma unroll
    for (int i = 0; i < 2; i++)
      g2l(kp + (size_t)(srow + i * 32) * HS + scol, Ks + tid * 8 + i * 2048);
#pragma unroll
    for (int i = 0; i < 2; i++)
      g2l(vbase + (size_t)(srow + i * 32) * SEQ + kt * 64 + scol, Vt + tid * 8 + i * 2048);
    __syncthreads();

    if (kt * 64 > rowbase + 31) continue;   // wave fully above causal band

    // S = Q K^T
    floatx4 S[2][4];
#pragma unroll
    for (int tj = 0; tj < 4; tj++) {
      short8 b0 = *(const short8*)&Ks[(tj * 16 + l16) * 64 + quad * 8];
      short8 b1 = *(const short8*)&Ks[(tj * 16 + l16) * 64 + 32 + quad * 8];
#pragma unroll
      for (int ih = 0; ih < 2; ih++) {
        floatx4 s = fzero;
        s = MFMA(qa[ih][0], b0, s);
        s = MFMA(qa[ih][1], b1, s);
        S[ih][tj] = s;
      }
    }
    if (kt * 64 + 63 > rowbase) {   // diagonal band: apply causal mask
#pragma unroll
      for (int ih = 0; ih < 2; ih++)
#pragma unroll
        for (int tj = 0; tj < 4; tj++) {
          int col = kt * 64 + tj * 16 + l16;
#pragma unroll
          for (int r = 0; r < 4; r++) {
            int row = rowbase + ih * 16 + quad * 4 + r;
            if (col > row) S[ih][tj][r] = -INFINITY;
          }
        }
    }
    // Online softmax (per ih half, 16-lane row groups).
    float alpha[2][4];
#pragma unroll
    for (int ih = 0; ih < 2; ih++) {
      float nm[4], rsum[4];
#pragma unroll
      for (int r = 0; r < 4; r++) {
        float mx = fmaxf(fmaxf(S[ih][0][r], S[ih][1][r]), fmaxf(S[ih][2][r], S[ih][3][r]));
#pragma unroll
        for (int off = 1; off < 16; off <<= 1)
          mx = fmaxf(mx, __shfl_xor(mx, off, 16));
        nm[r] = fmaxf(m_[ih][r], mx);
        alpha[ih][r] = __builtin_amdgcn_exp2f((m_[ih][r] - nm[r]) * c);
        rsum[r] = 0.f;
      }
#pragma unroll
      for (int tj = 0; tj < 4; tj++)
#pragma unroll
        for (int r = 0; r < 4; r++) {
          float pv = __builtin_amdgcn_exp2f((S[ih][tj][r] - nm[r]) * c);
          S[ih][tj][r] = pv;
          rsum[r] += pv;
        }
#pragma unroll
      for (int r = 0; r < 4; r++) {
#pragma unroll
        for (int off = 1; off < 16; off <<= 1)
          rsum[r] += __shfl_xor(rsum[r], off, 16);
        l_[ih][r] = l_[ih][r] * alpha[ih][r] + rsum[r];
        m_[ih][r] = nm[r];
      }
    }
    // P -> LDS, XOR-swizzled column blocks (wave-private rows, no barrier).
#pragma unroll
    for (int ih = 0; ih < 2; ih++)
#pragma unroll
      for (int tj = 0; tj < 4; tj++) {
        int cs = ((tj ^ quad) * 16) + l16;
#pragma unroll
        for (int r = 0; r < 4; r++)
          Ps[(wave * 32 + ih * 16 + quad * 4 + r) * 64 + cs] = (short)f2bf(S[ih][tj][r]);
      }
#pragma unroll
    for (int ih = 0; ih < 2; ih++)
#pragma unroll
      for (int tj = 0; tj < 4; tj++)
#pragma unroll
        for (int r = 0; r < 4; r++) O[ih][tj][r] *= alpha[ih][r];

    // O += P V
    short8 pa[2][2];
    const int sw = l16 >> 2;
#pragma unroll
    for (int ih = 0; ih < 2; ih++)
#pragma unroll
      for (int kh = 0; kh < 2; kh++) {
        int cb = kh * 2 + (quad >> 1);
        pa[ih][kh] = *(const short8*)&Ps[(wave * 32 + ih * 16 + l16) * 64 +
                                         ((cb ^ sw) * 16) + (quad & 1) * 8];
      }
#pragma unroll
    for (int tj = 0; tj < 4; tj++) {
      short8 b0 = *(const short8*)&Vt[(tj * 16 + l16) * 64 + quad * 8];
      short8 b1 = *(const short8*)&Vt[(tj * 16 + l16) * 64 + 32 + quad * 8];
#pragma unroll
      for (int ih = 0; ih < 2; ih++) {
        O[ih][tj] = MFMA(pa[ih][0], b0, O[ih][tj]);
        O[ih][tj] = MFMA(pa[ih][1], b1, O[ih][tj]);
      }
    }
  }

#pragma unroll
  for (int ih = 0; ih < 2; ih++)
#pragma unroll
    for (int r = 0; r < 4; r++) {
      float inv = 1.0f / l_[ih][r];
      int t = qt * 128 + wave * 32 + ih * 16 + quad * 4 + r;
#pragma unroll
      for (int tj = 0; tj < 4; tj++) {
        int e = tj * 16 + l16;
        o[((size_t)(b * SEQ + t)) * DM + h * HS + e] = f2bf(O[ih][tj][r] * inv);
      }
    }
}

// ---------- G3: output projection, 128x128 tiles ----------
__global__ __launch_bounds__(256) void out_gemm128(
    const unsigned short* __restrict__ A,    // [4096][1024] bf16
    const unsigned short* __restrict__ Bt,   // Wot [n][k]
    const float* __restrict__ bo,
    float* __restrict__ out) {
  __shared__ __align__(16) short As[128 * 64];
  __shared__ __align__(16) short Bs[128 * 64];
  const int tid = threadIdx.x;
  const int bm = blockIdx.x, bn = blockIdx.y;
  const int lane = tid & 63, wave = tid >> 6;
  const int quad = lane >> 4, l16 = lane & 15;
  const int wr = wave >> 1, wc = wave & 1;
  const floatx4 fzero = {0.f, 0.f, 0.f, 0.f};

  floatx4 acc[4][4];
#pragma unroll
  for (int i = 0; i < 4; i++)
#pragma unroll
    for (int j = 0; j < 4; j++) acc[i][j] = fzero;

  const int srow = tid >> 3, scol = (tid & 7) << 3;
  const unsigned short* Ag = A + (size_t)(bm * 128 + srow) * DM + scol;
  const unsigned short* Bg = Bt + (size_t)(bn * 128 + srow) * DM + scol;
  short* Ad = As + tid * 8;
  short* Bd = Bs + tid * 8;

  for (int k0 = 0; k0 < DM; k0 += 64) {
    __syncthreads();
#pragma unroll
    for (int i = 0; i < 4; i++) g2l(Ag + (size_t)i * 32 * DM + k0, Ad + i * 2048);
#pragma unroll
    for (int i = 0; i < 4; i++) g2l(Bg + (size_t)i * 32 * DM + k0, Bd + i * 2048);
    __syncthreads();

    short8 af[4][2], bf[4][2];
#pragma unroll
    for (int ti = 0; ti < 4; ti++)
#pragma unroll
      for (int kh = 0; kh < 2; kh++)
        af[ti][kh] = *(const short8*)&As[(wr * 64 + ti * 16 + l16) * 64 + kh * 32 + quad * 8];
#pragma unroll
    for (int tj = 0; tj < 4; tj++)
#pragma unroll
      for (int kh = 0; kh < 2; kh++)
        bf[tj][kh] = *(const short8*)&Bs[(wc * 64 + tj * 16 + l16) * 64 + kh * 32 + quad * 8];
#pragma unroll
    for (int ti = 0; ti < 4; ti++)
#pragma unroll
      for (int tj = 0; tj < 4; tj++) {
        acc[ti][tj] = MFMA(af[ti][0], bf[tj][0], acc[ti][tj]);
        acc[ti][tj] = MFMA(af[ti][1], bf[tj][1], acc[ti][tj]);
      }
  }

#pragma unroll
  for (int ti = 0; ti < 4; ti++)
#pragma unroll
    for (int tj = 0; tj < 4; tj++) {
      int n = bn * 128 + wc * 64 + tj * 16 + l16;
      float bias = bo[n];
#pragma unroll
      for (int r = 0; r < 4; r++) {
        int m = bm * 128 + wr * 64 + ti * 16 + quad * 4 + r;
        out[(size_t)m * DM + n] = acc[ti][tj][r] + bias;
      }
    }
}

extern "C" void kernel_launch(void* const* d_in, const int* in_sizes, int n_in,
                              void* d_out, int out_size, void* d_ws, size_t ws_size,
                              hipStream_t stream) {
  const float* x  = (const float*)d_in[0];
  const float* Wq = (const float*)d_in[1];
  const float* Wk = (const float*)d_in[2];
  const float* Wv = (const float*)d_in[3];
  const float* Wo = (const float*)d_in[4];
  const float* bo = (const float*)d_in[5];
  float* out = (float*)d_out;

  const size_t nx = (size_t)NB * SEQ * DM;          // 4M
  const size_t nw = (size_t)DM * DM;                // 1M
  unsigned short* xb  = (unsigned short*)d_ws;
  unsigned short* wtq = xb + nx;                    // wtq|wtk|wtv contiguous = Wcat
  unsigned short* wtk = wtq + nw;
  unsigned short* wtv = wtk + nw;
  unsigned short* wot = wtv + nw;
  unsigned short* qws = wot + nw;
  unsigned short* kws = qws + nx;
  unsigned short* vws = kws + nx;
  unsigned short* aws = vws + nx;

  dim3 blk(256);
  cast_x<<<dim3(1024), blk, 0, stream>>>(x, xb);
  prep_w<<<dim3(256, 4), blk, 0, stream>>>(Wq, Wk, Wv, Wo, wtq, wtk, wtv, wot);
  qkv_gemm128<<<dim3(32, 24), blk, 0, stream>>>(xb, wtq, qws, kws, vws);
  attn_kernel<<<dim3(SEQ / 128, NH, NB), blk, 0, stream>>>(qws, kws, vws, aws);
  out_gemm128<<<dim3(32, 8), blk, 0, stream>>>(aws, wot, bo, out);
}

// Round 4
// 202.916 us; speedup vs baseline: 1.6433x; 1.1019x over previous
//
#include <hip/hip_runtime.h>
#include <math.h>

#define NB 4
#define SEQ 1024
#define DM 1024
#define NH 16
#define HS 64

typedef __attribute__((ext_vector_type(8))) short short8;
typedef __attribute__((ext_vector_type(4))) short short4v;
typedef __attribute__((ext_vector_type(4))) float floatx4;

#define MFMA(a, b, c) __builtin_amdgcn_mfma_f32_16x16x32_bf16((a), (b), (c), 0, 0, 0)

static __device__ __forceinline__ unsigned short f2bf(float f) {
  unsigned int u = __float_as_uint(f);
  u += 0x7FFFu + ((u >> 16) & 1u);   // RNE
  return (unsigned short)(u >> 16);
}

// 16B async global->LDS. LDS dest = wave-uniform base + lane*16.
static __device__ __forceinline__ void g2l(const unsigned short* g, short* l) {
  __builtin_amdgcn_global_load_lds(
      (const __attribute__((address_space(1))) void*)g,
      (__attribute__((address_space(3))) void*)l, 16, 0, 0);
}

// XOR swizzle: LDS 16B-block blk of row r holds global 16B-block (blk ^ (r&7)).
// Staging source column (shorts) for thread tid (row = tid>>3, blk = tid&7):
#define SWZ_SRC(tid) ((((tid) & 7) ^ (((tid) >> 3) & 7)) << 3)
// Fragment read offset (shorts) for 16B-block B of row r:
#define SWZ_RD(B, r) ((((B) ^ ((r) & 7)) << 3))

// ---------- P1: cast x (f32 -> bf16) ----------
__global__ __launch_bounds__(256) void cast_x(
    const float* __restrict__ x, unsigned short* __restrict__ xb) {
  int base = blockIdx.x * 1024;
#pragma unroll
  for (int i = 0; i < 4; i++) {
    int idx4 = base + threadIdx.x + i * 256;
    float4 v = *(const float4*)(x + (size_t)idx4 * 4);
    short4v o;
    o[0] = (short)f2bf(v.x); o[1] = (short)f2bf(v.y);
    o[2] = (short)f2bf(v.z); o[3] = (short)f2bf(v.w);
    *(short4v*)(xb + (size_t)idx4 * 4) = o;
  }
}

// ---------- P2: transpose+cast weights ----------
__global__ __launch_bounds__(256) void prep_w(
    const float* __restrict__ Wq, const float* __restrict__ Wk,
    const float* __restrict__ Wv, const float* __restrict__ Wo,
    unsigned short* __restrict__ Wtq, unsigned short* __restrict__ Wtk,
    unsigned short* __restrict__ Wtv, unsigned short* __restrict__ Wot) {
  __shared__ __align__(16) short Ts[64 * 72];
  const int tid = threadIdx.x;
  const int mat = blockIdx.y;
  const float* src;
  unsigned short* dst;
  int r0, c0;
  if (mat < 3) {
    src = (mat == 0) ? Wq : (mat == 1) ? Wk : Wv;
    dst = (mat == 0) ? Wtq : (mat == 1) ? Wtk : Wtv;
    int h = blockIdx.x >> 4;
    int d0 = (blockIdx.x & 15) * 64;
    src += (size_t)(h * DM + d0) * HS;
    dst += (size_t)(h * HS) * DM + d0;
    r0 = HS;  c0 = DM;
  } else {
    src = Wo; dst = Wot;
    int k0 = (blockIdx.x >> 4) * 64;
    int n0 = (blockIdx.x & 15) * 64;
    src += (size_t)k0 * DM + n0;
    dst += (size_t)n0 * DM + k0;
    r0 = DM;  c0 = DM;
  }
#pragma unroll
  for (int i = 0; i < 4; i++) {
    int p = tid + i * 256;
    int row = p >> 4, c4 = (p & 15) << 2;
    float4 v = *(const float4*)(src + (size_t)row * r0 + c4);
    Ts[(c4 + 0) * 72 + row] = (short)f2bf(v.x);
    Ts[(c4 + 1) * 72 + row] = (short)f2bf(v.y);
    Ts[(c4 + 2) * 72 + row] = (short)f2bf(v.z);
    Ts[(c4 + 3) * 72 + row] = (short)f2bf(v.w);
  }
  __syncthreads();
#pragma unroll
  for (int i = 0; i < 2; i++) {
    int p = tid + i * 256;
    int row = p >> 3, c8 = (p & 7) << 3;
    *(short8*)(dst + (size_t)row * c0 + c8) = *(const short8*)&Ts[row * 72 + c8];
  }
}

// ---------- G1: fused QKV as one 4096x3072x1024 GEMM, 128x128 tiles ----------
__global__ __launch_bounds__(256) void qkv_gemm128(
    const unsigned short* __restrict__ xb,    // [4096][1024]
    const unsigned short* __restrict__ Wcat,  // [3072][1024] = Wtq|Wtk|Wtv
    unsigned short* __restrict__ qo,          // [B,H,T,HS]
    unsigned short* __restrict__ ko,          // [B,H,T,HS]
    unsigned short* __restrict__ vo) {        // [B,H,HS,T]
  __shared__ __align__(16) short As[128 * 64];
  __shared__ __align__(16) short Bs[128 * 64];
  const int tid = threadIdx.x;
  const int bm = blockIdx.x, bn = blockIdx.y;
  const int lane = tid & 63, wave = tid >> 6;
  const int quad = lane >> 4, l16 = lane & 15;
  const int wr = wave >> 1, wc = wave & 1;
  const int l7 = l16 & 7;
  const floatx4 fzero = {0.f, 0.f, 0.f, 0.f};

  floatx4 acc[4][4];
#pragma unroll
  for (int i = 0; i < 4; i++)
#pragma unroll
    for (int j = 0; j < 4; j++) acc[i][j] = fzero;

  const int srow = tid >> 3;
  const int scolw = SWZ_SRC(tid);
  const unsigned short* Ag = xb + (size_t)(bm * 128 + srow) * DM + scolw;
  const unsigned short* Bg = Wcat + (size_t)(bn * 128 + srow) * DM + scolw;
  short* Ad = As + tid * 8;
  short* Bd = Bs + tid * 8;

  for (int k0 = 0; k0 < DM; k0 += 64) {
    __syncthreads();
#pragma unroll
    for (int i = 0; i < 4; i++) g2l(Ag + (size_t)i * 32 * DM + k0, Ad + i * 2048);
#pragma unroll
    for (int i = 0; i < 4; i++) g2l(Bg + (size_t)i * 32 * DM + k0, Bd + i * 2048);
    __syncthreads();

    short8 af[4][2], bf[4][2];
#pragma unroll
    for (int ti = 0; ti < 4; ti++)
#pragma unroll
      for (int kh = 0; kh < 2; kh++)
        af[ti][kh] = *(const short8*)&As[(wr * 64 + ti * 16 + l16) * 64 +
                                          SWZ_RD(kh * 4 + quad, l7)];
#pragma unroll
    for (int tj = 0; tj < 4; tj++)
#pragma unroll
      for (int kh = 0; kh < 2; kh++)
        bf[tj][kh] = *(const short8*)&Bs[(wc * 64 + tj * 16 + l16) * 64 +
                                          SWZ_RD(kh * 4 + quad, l7)];
#pragma unroll
    for (int ti = 0; ti < 4; ti++)
#pragma unroll
      for (int tj = 0; tj < 4; tj++) {
        acc[ti][tj] = MFMA(af[ti][0], bf[tj][0], acc[ti][tj]);
        acc[ti][tj] = MFMA(af[ti][1], bf[tj][1], acc[ti][tj]);
      }
  }

  const int mat = bn >> 3;
  const int mbase = bm * 128 + wr * 64 + quad * 4;
  const int nn0 = (bn & 7) * 128 + wc * 64;
  if (mat < 2) {
    unsigned short* dst = (mat == 0) ? qo : ko;
#pragma unroll
    for (int ti = 0; ti < 4; ti++)
#pragma unroll
      for (int tj = 0; tj < 4; tj++) {
        int ecol = nn0 + tj * 16 + l16;
        int h = ecol >> 6, e = ecol & 63;
#pragma unroll
        for (int r = 0; r < 4; r++) {
          int m = mbase + ti * 16 + r;
          int b = m >> 10, t = m & (SEQ - 1);
          dst[((size_t)(b * NH + h) * SEQ + t) * HS + e] = f2bf(acc[ti][tj][r]);
        }
      }
  } else {
#pragma unroll
    for (int ti = 0; ti < 4; ti++)
#pragma unroll
      for (int tj = 0; tj < 4; tj++) {
        int ecol = nn0 + tj * 16 + l16;
        int h = ecol >> 6, e = ecol & 63;
        int m0 = mbase + ti * 16;
        int b = m0 >> 10, t0 = m0 & (SEQ - 1);
        short4v pv;
#pragma unroll
        for (int r = 0; r < 4; r++) pv[r] = (short)f2bf(acc[ti][tj][r]);
        *(short4v*)&vo[((size_t)(b * NH + h) * HS + e) * SEQ + t0] = pv;
      }
  }
}

// ---------- G2: flash attention, 128-row Q tile / block ----------
__global__ __launch_bounds__(256) void attn_kernel(
    const unsigned short* __restrict__ q,   // [B,H,T,HS]
    const unsigned short* __restrict__ k,   // [B,H,T,HS]
    const unsigned short* __restrict__ v,   // [B,H,HS,T]
    unsigned short* __restrict__ o)         // [B,T,H*HS]
{
  __shared__ __align__(16) short Qs[128 * 64];
  __shared__ __align__(16) short Ks[64 * 64];
  __shared__ __align__(16) short Vt[64 * 64];
  __shared__ __align__(16) short Ps[128 * 76];
  const int tid = threadIdx.x;
  const int qt = (int)(gridDim.x - 1 - blockIdx.x);   // big tiles dispatch first
  const int h = blockIdx.y, b = blockIdx.z;
  const int lane = tid & 63, wave = tid >> 6;
  const int quad = lane >> 4, l16 = lane & 15;
  const int l7 = l16 & 7;
  const size_t bh = (size_t)(b * NH + h) * SEQ * HS;
  const unsigned short* qp = q + bh + (size_t)qt * 128 * HS;
  const unsigned short* kbase = k + bh;
  const unsigned short* vbase = v + (size_t)(b * NH + h) * HS * SEQ;
  const floatx4 fzero = {0.f, 0.f, 0.f, 0.f};
  const float c = 0.125f * 1.44269504089f;   // scale * log2(e)
  const int srow = tid >> 3;
  const int scolw = SWZ_SRC(tid);

  // Stage Q once (swizzled); hold fragments in registers.
#pragma unroll
  for (int i = 0; i < 4; i++)
    g2l(qp + (size_t)(srow + i * 32) * HS + scolw, Qs + tid * 8 + i * 2048);
  __syncthreads();
  short8 qa[2][2];
#pragma unroll
  for (int ih = 0; ih < 2; ih++)
#pragma unroll
    for (int kh = 0; kh < 2; kh++)
      qa[ih][kh] = *(const short8*)&Qs[(wave * 32 + ih * 16 + l16) * 64 +
                                        SWZ_RD(kh * 4 + quad, l7)];

  const int rowbase = qt * 128 + wave * 32;
  float m_[2][4], l_[2][4];
  floatx4 O[2][4];
#pragma unroll
  for (int ih = 0; ih < 2; ih++)
#pragma unroll
    for (int r = 0; r < 4; r++) { m_[ih][r] = -INFINITY; l_[ih][r] = 0.f; }
#pragma unroll
  for (int ih = 0; ih < 2; ih++)
#pragma unroll
    for (int tj = 0; tj < 4; tj++) O[ih][tj] = fzero;

  const int ktmax = 2 * qt + 1;
  for (int kt = 0; kt <= ktmax; kt++) {
    __syncthreads();
    const unsigned short* kp = kbase + (size_t)kt * 64 * HS;
#pragma unroll
    for (int i = 0; i < 2; i++)
      g2l(kp + (size_t)(srow + i * 32) * HS + scolw, Ks + tid * 8 + i * 2048);
#pragma unroll
    for (int i = 0; i < 2; i++)
      g2l(vbase + (size_t)(srow + i * 32) * SEQ + kt * 64 + scolw,
          Vt + tid * 8 + i * 2048);
    __syncthreads();

    if (kt * 64 > rowbase + 31) continue;   // wave fully above causal band

    // S = Q K^T
    floatx4 S[2][4];
#pragma unroll
    for (int tj = 0; tj < 4; tj++) {
      short8 b0 = *(const short8*)&Ks[(tj * 16 + l16) * 64 + SWZ_RD(quad, l7)];
      short8 b1 = *(const short8*)&Ks[(tj * 16 + l16) * 64 + SWZ_RD(4 + quad, l7)];
#pragma unroll
      for (int ih = 0; ih < 2; ih++) {
        floatx4 s = fzero;
        s = MFMA(qa[ih][0], b0, s);
        s = MFMA(qa[ih][1], b1, s);
        S[ih][tj] = s;
      }
    }
    if (kt * 64 + 63 > rowbase) {   // diagonal band: causal mask
#pragma unroll
      for (int ih = 0; ih < 2; ih++)
#pragma unroll
        for (int tj = 0; tj < 4; tj++) {
          int col = kt * 64 + tj * 16 + l16;
#pragma unroll
          for (int r = 0; r < 4; r++) {
            int row = rowbase + ih * 16 + quad * 4 + r;
            if (col > row) S[ih][tj][r] = -INFINITY;
          }
        }
    }
    // Online softmax (per ih half, 16-lane row groups).
    float alpha[2][4];
#pragma unroll
    for (int ih = 0; ih < 2; ih++) {
      float nm[4], rsum[4];
#pragma unroll
      for (int r = 0; r < 4; r++) {
        float mx = fmaxf(fmaxf(S[ih][0][r], S[ih][1][r]), fmaxf(S[ih][2][r], S[ih][3][r]));
#pragma unroll
        for (int off = 1; off < 16; off <<= 1)
          mx = fmaxf(mx, __shfl_xor(mx, off, 16));
        nm[r] = fmaxf(m_[ih][r], mx);
        alpha[ih][r] = __builtin_amdgcn_exp2f((m_[ih][r] - nm[r]) * c);
        rsum[r] = 0.f;
      }
#pragma unroll
      for (int tj = 0; tj < 4; tj++)
#pragma unroll
        for (int r = 0; r < 4; r++) {
          float pv = __builtin_amdgcn_exp2f((S[ih][tj][r] - nm[r]) * c);
          S[ih][tj][r] = pv;
          rsum[r] += pv;
        }
#pragma unroll
      for (int r = 0; r < 4; r++) {
#pragma unroll
        for (int off = 1; off < 16; off <<= 1)
          rsum[r] += __shfl_xor(rsum[r], off, 16);
        l_[ih][r] = l_[ih][r] * alpha[ih][r] + rsum[r];
        m_[ih][r] = nm[r];
      }
    }
    // P -> LDS (padded stride 76; wave-private rows, no barrier needed).
#pragma unroll
    for (int ih = 0; ih < 2; ih++)
#pragma unroll
      for (int tj = 0; tj < 4; tj++)
#pragma unroll
        for (int r = 0; r < 4; r++)
          Ps[(wave * 32 + ih * 16 + quad * 4 + r) * 76 + tj * 16 + l16] =
              (short)f2bf(S[ih][tj][r]);
#pragma unroll
    for (int ih = 0; ih < 2; ih++)
#pragma unroll
      for (int tj = 0; tj < 4; tj++)
#pragma unroll
        for (int r = 0; r < 4; r++) O[ih][tj][r] *= alpha[ih][r];

    // O += P V
    short8 pa[2][2];
#pragma unroll
    for (int ih = 0; ih < 2; ih++)
#pragma unroll
      for (int kh = 0; kh < 2; kh++)
        pa[ih][kh] = *(const short8*)&Ps[(wave * 32 + ih * 16 + l16) * 76 +
                                          kh * 32 + quad * 8];
#pragma unroll
    for (int tj = 0; tj < 4; tj++) {
      short8 b0 = *(const short8*)&Vt[(tj * 16 + l16) * 64 + SWZ_RD(quad, l7)];
      short8 b1 = *(const short8*)&Vt[(tj * 16 + l16) * 64 + SWZ_RD(4 + quad, l7)];
#pragma unroll
      for (int ih = 0; ih < 2; ih++) {
        O[ih][tj] = MFMA(pa[ih][0], b0, O[ih][tj]);
        O[ih][tj] = MFMA(pa[ih][1], b1, O[ih][tj]);
      }
    }
  }

#pragma unroll
  for (int ih = 0; ih < 2; ih++)
#pragma unroll
    for (int r = 0; r < 4; r++) {
      float inv = 1.0f / l_[ih][r];
      int t = qt * 128 + wave * 32 + ih * 16 + quad * 4 + r;
#pragma unroll
      for (int tj = 0; tj < 4; tj++) {
        int e = tj * 16 + l16;
        o[((size_t)(b * SEQ + t)) * DM + h * HS + e] = f2bf(O[ih][tj][r] * inv);
      }
    }
}

// ---------- G3: output projection, 128x128 tiles ----------
__global__ __launch_bounds__(256) void out_gemm128(
    const unsigned short* __restrict__ A,    // [4096][1024] bf16
    const unsigned short* __restrict__ Bt,   // Wot [n][k]
    const float* __restrict__ bo,
    float* __restrict__ out) {
  __shared__ __align__(16) short As[128 * 64];
  __shared__ __align__(16) short Bs[128 * 64];
  const int tid = threadIdx.x;
  const int bm = blockIdx.x, bn = blockIdx.y;
  const int lane = tid & 63, wave = tid >> 6;
  const int quad = lane >> 4, l16 = lane & 15;
  const int wr = wave >> 1, wc = wave & 1;
  const int l7 = l16 & 7;
  const floatx4 fzero = {0.f, 0.f, 0.f, 0.f};

  floatx4 acc[4][4];
#pragma unroll
  for (int i = 0; i < 4; i++)
#pragma unroll
    for (int j = 0; j < 4; j++) acc[i][j] = fzero;

  const int srow = tid >> 3;
  const int scolw = SWZ_SRC(tid);
  const unsigned short* Ag = A + (size_t)(bm * 128 + srow) * DM + scolw;
  const unsigned short* Bg = Bt + (size_t)(bn * 128 + srow) * DM + scolw;
  short* Ad = As + tid * 8;
  short* Bd = Bs + tid * 8;

  for (int k0 = 0; k0 < DM; k0 += 64) {
    __syncthreads();
#pragma unroll
    for (int i = 0; i < 4; i++) g2l(Ag + (size_t)i * 32 * DM + k0, Ad + i * 2048);
#pragma unroll
    for (int i = 0; i < 4; i++) g2l(Bg + (size_t)i * 32 * DM + k0, Bd + i * 2048);
    __syncthreads();

    short8 af[4][2], bf[4][2];
#pragma unroll
    for (int ti = 0; ti < 4; ti++)
#pragma unroll
      for (int kh = 0; kh < 2; kh++)
        af[ti][kh] = *(const short8*)&As[(wr * 64 + ti * 16 + l16) * 64 +
                                          SWZ_RD(kh * 4 + quad, l7)];
#pragma unroll
    for (int tj = 0; tj < 4; tj++)
#pragma unroll
      for (int kh = 0; kh < 2; kh++)
        bf[tj][kh] = *(const short8*)&Bs[(wc * 64 + tj * 16 + l16) * 64 +
                                          SWZ_RD(kh * 4 + quad, l7)];
#pragma unroll
    for (int ti = 0; ti < 4; ti++)
#pragma unroll
      for (int tj = 0; tj < 4; tj++) {
        acc[ti][tj] = MFMA(af[ti][0], bf[tj][0], acc[ti][tj]);
        acc[ti][tj] = MFMA(af[ti][1], bf[tj][1], acc[ti][tj]);
      }
  }

#pragma unroll
  for (int ti = 0; ti < 4; ti++)
#pragma unroll
    for (int tj = 0; tj < 4; tj++) {
      int n = bn * 128 + wc * 64 + tj * 16 + l16;
      float bias = bo[n];
#pragma unroll
      for (int r = 0; r < 4; r++) {
        int m = bm * 128 + wr * 64 + ti * 16 + quad * 4 + r;
        out[(size_t)m * DM + n] = acc[ti][tj][r] + bias;
      }
    }
}

extern "C" void kernel_launch(void* const* d_in, const int* in_sizes, int n_in,
                              void* d_out, int out_size, void* d_ws, size_t ws_size,
                              hipStream_t stream) {
  const float* x  = (const float*)d_in[0];
  const float* Wq = (const float*)d_in[1];
  const float* Wk = (const float*)d_in[2];
  const float* Wv = (const float*)d_in[3];
  const float* Wo = (const float*)d_in[4];
  const float* bo = (const float*)d_in[5];
  float* out = (float*)d_out;

  const size_t nx = (size_t)NB * SEQ * DM;          // 4M
  const size_t nw = (size_t)DM * DM;                // 1M
  unsigned short* xb  = (unsigned short*)d_ws;
  unsigned short* wtq = xb + nx;                    // wtq|wtk|wtv contiguous
  unsigned short* wtk = wtq + nw;
  unsigned short* wtv = wtk + nw;
  unsigned short* wot = wtv + nw;
  unsigned short* qws = wot + nw;
  unsigned short* kws = qws + nx;
  unsigned short* vws = kws + nx;
  unsigned short* aws = vws + nx;

  dim3 blk(256);
  cast_x<<<dim3(1024), blk, 0, stream>>>(x, xb);
  prep_w<<<dim3(256, 4), blk, 0, stream>>>(Wq, Wk, Wv, Wo, wtq, wtk, wtv, wot);
  qkv_gemm128<<<dim3(32, 24), blk, 0, stream>>>(xb, wtq, qws, kws, vws);
  attn_kernel<<<dim3(SEQ / 128, NH, NB), blk, 0, stream>>>(qws, kws, vws, aws);
  out_gemm128<<<dim3(32, 8), blk, 0, stream>>>(aws, wot, bo, out);
}

// Round 5
// 173.523 us; speedup vs baseline: 1.9217x; 1.1694x over previous
//
#include <hip/hip_runtime.h>
#include <math.h>

#define NB 4
#define SEQ 1024
#define DM 1024
#define NH 16
#define HS 64

typedef __attribute__((ext_vector_type(8))) short short8;
typedef __attribute__((ext_vector_type(4))) short short4v;
typedef __attribute__((ext_vector_type(4))) float floatx4;

#define MFMA(a, b, c) __builtin_amdgcn_mfma_f32_16x16x32_bf16((a), (b), (c), 0, 0, 0)

static __device__ __forceinline__ unsigned short f2bf(float f) {
  unsigned int u = __float_as_uint(f);
  u += 0x7FFFu + ((u >> 16) & 1u);   // RNE
  return (unsigned short)(u >> 16);
}

// 16B async global->LDS. LDS dest = wave-uniform base + lane*16.
static __device__ __forceinline__ void g2l(const unsigned short* g, short* l) {
  __builtin_amdgcn_global_load_lds(
      (const __attribute__((address_space(1))) void*)g,
      (__attribute__((address_space(3))) void*)l, 16, 0, 0);
}

// XOR swizzle: LDS 16B-block blk of row r holds global 16B-block (blk ^ (r&7)).
#define SWZ_SRC(tid) ((((tid) & 7) ^ (((tid) >> 3) & 7)) << 3)
#define SWZ_RD(B, r) ((((B) ^ ((r) & 7)) << 3))

// ---------- P1: cast x (f32 -> bf16) ----------
__global__ __launch_bounds__(256) void cast_x(
    const float* __restrict__ x, unsigned short* __restrict__ xb) {
  int base = blockIdx.x * 1024;
#pragma unroll
  for (int i = 0; i < 4; i++) {
    int idx4 = base + threadIdx.x + i * 256;
    float4 v = *(const float4*)(x + (size_t)idx4 * 4);
    short4v o;
    o[0] = (short)f2bf(v.x); o[1] = (short)f2bf(v.y);
    o[2] = (short)f2bf(v.z); o[3] = (short)f2bf(v.w);
    *(short4v*)(xb + (size_t)idx4 * 4) = o;
  }
}

// ---------- P2: transpose+cast weights ----------
__global__ __launch_bounds__(256) void prep_w(
    const float* __restrict__ Wq, const float* __restrict__ Wk,
    const float* __restrict__ Wv, const float* __restrict__ Wo,
    unsigned short* __restrict__ Wtq, unsigned short* __restrict__ Wtk,
    unsigned short* __restrict__ Wtv, unsigned short* __restrict__ Wot) {
  __shared__ __align__(16) short Ts[64 * 72];
  const int tid = threadIdx.x;
  const int mat = blockIdx.y;
  const float* src;
  unsigned short* dst;
  int r0, c0;
  if (mat < 3) {
    src = (mat == 0) ? Wq : (mat == 1) ? Wk : Wv;
    dst = (mat == 0) ? Wtq : (mat == 1) ? Wtk : Wtv;
    int h = blockIdx.x >> 4;
    int d0 = (blockIdx.x & 15) * 64;
    src += (size_t)(h * DM + d0) * HS;
    dst += (size_t)(h * HS) * DM + d0;
    r0 = HS;  c0 = DM;
  } else {
    src = Wo; dst = Wot;
    int k0 = (blockIdx.x >> 4) * 64;
    int n0 = (blockIdx.x & 15) * 64;
    src += (size_t)k0 * DM + n0;
    dst += (size_t)n0 * DM + k0;
    r0 = DM;  c0 = DM;
  }
#pragma unroll
  for (int i = 0; i < 4; i++) {
    int p = tid + i * 256;
    int row = p >> 4, c4 = (p & 15) << 2;
    float4 v = *(const float4*)(src + (size_t)row * r0 + c4);
    Ts[(c4 + 0) * 72 + row] = (short)f2bf(v.x);
    Ts[(c4 + 1) * 72 + row] = (short)f2bf(v.y);
    Ts[(c4 + 2) * 72 + row] = (short)f2bf(v.z);
    Ts[(c4 + 3) * 72 + row] = (short)f2bf(v.w);
  }
  __syncthreads();
#pragma unroll
  for (int i = 0; i < 2; i++) {
    int p = tid + i * 256;
    int row = p >> 3, c8 = (p & 7) << 3;
    *(short8*)(dst + (size_t)row * c0 + c8) = *(const short8*)&Ts[row * 72 + c8];
  }
}

// ---------- G1: fused QKV as one 4096x3072x1024 GEMM, 128x128 tiles ----------
__global__ __launch_bounds__(256) void qkv_gemm128(
    const unsigned short* __restrict__ xb,
    const unsigned short* __restrict__ Wcat,
    unsigned short* __restrict__ qo,
    unsigned short* __restrict__ ko,
    unsigned short* __restrict__ vo) {
  __shared__ __align__(16) short As[128 * 64];
  __shared__ __align__(16) short Bs[128 * 64];
  const int tid = threadIdx.x;
  const int bm = blockIdx.x, bn = blockIdx.y;
  const int lane = tid & 63, wave = tid >> 6;
  const int quad = lane >> 4, l16 = lane & 15;
  const int wr = wave >> 1, wc = wave & 1;
  const int l7 = l16 & 7;
  const floatx4 fzero = {0.f, 0.f, 0.f, 0.f};

  floatx4 acc[4][4];
#pragma unroll
  for (int i = 0; i < 4; i++)
#pragma unroll
    for (int j = 0; j < 4; j++) acc[i][j] = fzero;

  const int srow = tid >> 3;
  const int scolw = SWZ_SRC(tid);
  const unsigned short* Ag = xb + (size_t)(bm * 128 + srow) * DM + scolw;
  const unsigned short* Bg = Wcat + (size_t)(bn * 128 + srow) * DM + scolw;
  short* Ad = As + tid * 8;
  short* Bd = Bs + tid * 8;

  for (int k0 = 0; k0 < DM; k0 += 64) {
    __syncthreads();
#pragma unroll
    for (int i = 0; i < 4; i++) g2l(Ag + (size_t)i * 32 * DM + k0, Ad + i * 2048);
#pragma unroll
    for (int i = 0; i < 4; i++) g2l(Bg + (size_t)i * 32 * DM + k0, Bd + i * 2048);
    __syncthreads();

    short8 af[4][2], bf[4][2];
#pragma unroll
    for (int ti = 0; ti < 4; ti++)
#pragma unroll
      for (int kh = 0; kh < 2; kh++)
        af[ti][kh] = *(const short8*)&As[(wr * 64 + ti * 16 + l16) * 64 +
                                          SWZ_RD(kh * 4 + quad, l7)];
#pragma unroll
    for (int tj = 0; tj < 4; tj++)
#pragma unroll
      for (int kh = 0; kh < 2; kh++)
        bf[tj][kh] = *(const short8*)&Bs[(wc * 64 + tj * 16 + l16) * 64 +
                                          SWZ_RD(kh * 4 + quad, l7)];
#pragma unroll
    for (int ti = 0; ti < 4; ti++)
#pragma unroll
      for (int tj = 0; tj < 4; tj++) {
        acc[ti][tj] = MFMA(af[ti][0], bf[tj][0], acc[ti][tj]);
        acc[ti][tj] = MFMA(af[ti][1], bf[tj][1], acc[ti][tj]);
      }
  }

  const int mat = bn >> 3;
  const int mbase = bm * 128 + wr * 64 + quad * 4;
  const int nn0 = (bn & 7) * 128 + wc * 64;
  if (mat < 2) {
    unsigned short* dst = (mat == 0) ? qo : ko;
#pragma unroll
    for (int ti = 0; ti < 4; ti++)
#pragma unroll
      for (int tj = 0; tj < 4; tj++) {
        int ecol = nn0 + tj * 16 + l16;
        int h = ecol >> 6, e = ecol & 63;
#pragma unroll
        for (int r = 0; r < 4; r++) {
          int m = mbase + ti * 16 + r;
          int b = m >> 10, t = m & (SEQ - 1);
          dst[((size_t)(b * NH + h) * SEQ + t) * HS + e] = f2bf(acc[ti][tj][r]);
        }
      }
  } else {
#pragma unroll
    for (int ti = 0; ti < 4; ti++)
#pragma unroll
      for (int tj = 0; tj < 4; tj++) {
        int ecol = nn0 + tj * 16 + l16;
        int h = ecol >> 6, e = ecol & 63;
        int m0 = mbase + ti * 16;
        int b = m0 >> 10, t0 = m0 & (SEQ - 1);
        short4v pv;
#pragma unroll
        for (int r = 0; r < 4; r++) pv[r] = (short)f2bf(acc[ti][tj][r]);
        *(short4v*)&vo[((size_t)(b * NH + h) * HS + e) * SEQ + t0] = pv;
      }
  }
}

// ---------- G2: flash attention, fixed-max softmax, dbuf K/V ----------
__global__ __launch_bounds__(256) void attn_kernel(
    const unsigned short* __restrict__ q,   // [B,H,T,HS]
    const unsigned short* __restrict__ k,   // [B,H,T,HS]
    const unsigned short* __restrict__ v,   // [B,H,HS,T]
    unsigned short* __restrict__ o)         // [B,T,H*HS]
{
  __shared__ __align__(16) short Qs[128 * 64];
  __shared__ __align__(16) short Ks[2][64 * 64];
  __shared__ __align__(16) short Vt[2][64 * 64];
  __shared__ __align__(16) short Ps[128 * 76];
  const int tid = threadIdx.x;
  // Balanced decode: lid c and c+256 have complementary qt (sum=7) so each
  // CU's two co-resident blocks do 18 iteration-units total.
  const int lid = (int)blockIdx.x;
  const int jj = lid & 3, half = lid >> 8, pp = (lid >> 2) & 63;
  const int qt = half ? jj : 7 - jj;
  const int h = pp & 15, b = pp >> 4;
  const int lane = tid & 63, wave = tid >> 6;
  const int quad = lane >> 4, l16 = lane & 15;
  const int l7 = l16 & 7;
  const size_t bh = (size_t)(b * NH + h) * SEQ * HS;
  const unsigned short* qp = q + bh + (size_t)qt * 128 * HS;
  const unsigned short* kbase = k + bh;
  const unsigned short* vbase = v + (size_t)(b * NH + h) * HS * SEQ;
  const floatx4 fzero = {0.f, 0.f, 0.f, 0.f};
  const float c2 = 0.125f * 1.44269504089f;   // scale * log2(e)
  const float C0 = 16.0f * 1.44269504089f;    // fixed softmax max (statistical bound)
  const int srow = tid >> 3;
  const int scolw = SWZ_SRC(tid);

  // Stage Q (swizzled) + K/V tile 0, one barrier.
#pragma unroll
  for (int i = 0; i < 4; i++)
    g2l(qp + (size_t)(srow + i * 32) * HS + scolw, Qs + tid * 8 + i * 2048);
  {
    const unsigned short* kp = kbase;
#pragma unroll
    for (int i = 0; i < 2; i++)
      g2l(kp + (size_t)(srow + i * 32) * HS + scolw, &Ks[0][tid * 8 + i * 2048]);
#pragma unroll
    for (int i = 0; i < 2; i++)
      g2l(vbase + (size_t)(srow + i * 32) * SEQ + scolw, &Vt[0][tid * 8 + i * 2048]);
  }
  __syncthreads();
  short8 qa[2][2];
#pragma unroll
  for (int ih = 0; ih < 2; ih++)
#pragma unroll
    for (int kh = 0; kh < 2; kh++)
      qa[ih][kh] = *(const short8*)&Qs[(wave * 32 + ih * 16 + l16) * 64 +
                                        SWZ_RD(kh * 4 + quad, l7)];

  const int rowbase = qt * 128 + wave * 32;
  float l_[2][4];
  floatx4 O[2][4];
#pragma unroll
  for (int ih = 0; ih < 2; ih++)
#pragma unroll
    for (int r = 0; r < 4; r++) l_[ih][r] = 0.f;
#pragma unroll
  for (int ih = 0; ih < 2; ih++)
#pragma unroll
    for (int tj = 0; tj < 4; tj++) O[ih][tj] = fzero;

  const int ktmax = 2 * qt + 1;
  for (int kt = 0; kt <= ktmax; kt++) {
    const int cur = kt & 1;
    // Prefetch next tile into the other buffer (drained by next barrier).
    if (kt < ktmax) {
      const unsigned short* kp = kbase + (size_t)(kt + 1) * 64 * HS;
#pragma unroll
      for (int i = 0; i < 2; i++)
        g2l(kp + (size_t)(srow + i * 32) * HS + scolw,
            &Ks[1 - cur][tid * 8 + i * 2048]);
#pragma unroll
      for (int i = 0; i < 2; i++)
        g2l(vbase + (size_t)(srow + i * 32) * SEQ + (kt + 1) * 64 + scolw,
            &Vt[1 - cur][tid * 8 + i * 2048]);
    }

    if (kt * 64 <= rowbase + 31) {   // wave intersects causal band
      // S = Q K^T
      floatx4 S[2][4];
#pragma unroll
      for (int tj = 0; tj < 4; tj++) {
        short8 b0 = *(const short8*)&Ks[cur][(tj * 16 + l16) * 64 + SWZ_RD(quad, l7)];
        short8 b1 = *(const short8*)&Ks[cur][(tj * 16 + l16) * 64 + SWZ_RD(4 + quad, l7)];
#pragma unroll
        for (int ih = 0; ih < 2; ih++) {
          floatx4 s = fzero;
          s = MFMA(qa[ih][0], b0, s);
          s = MFMA(qa[ih][1], b1, s);
          S[ih][tj] = s;
        }
      }
      if (kt * 64 + 63 > rowbase) {   // diagonal band: causal mask
#pragma unroll
        for (int ih = 0; ih < 2; ih++)
#pragma unroll
          for (int tj = 0; tj < 4; tj++) {
            int col = kt * 64 + tj * 16 + l16;
#pragma unroll
            for (int r = 0; r < 4; r++) {
              int row = rowbase + ih * 16 + quad * 4 + r;
              if (col > row) S[ih][tj][r] = -INFINITY;
            }
          }
      }
      // Fixed-max exp; accumulate per-lane partial row sums (reduced at end).
#pragma unroll
      for (int ih = 0; ih < 2; ih++)
#pragma unroll
        for (int tj = 0; tj < 4; tj++)
#pragma unroll
          for (int r = 0; r < 4; r++) {
            float pv = __builtin_amdgcn_exp2f(S[ih][tj][r] * c2 - C0);
            S[ih][tj][r] = pv;
            l_[ih][r] += pv;
          }
      // P -> LDS (padded stride 76; wave-private rows, no barrier needed).
#pragma unroll
      for (int ih = 0; ih < 2; ih++)
#pragma unroll
        for (int tj = 0; tj < 4; tj++)
#pragma unroll
          for (int r = 0; r < 4; r++)
            Ps[(wave * 32 + ih * 16 + quad * 4 + r) * 76 + tj * 16 + l16] =
                (short)f2bf(S[ih][tj][r]);

      // O += P V
      short8 pa[2][2];
#pragma unroll
      for (int ih = 0; ih < 2; ih++)
#pragma unroll
        for (int kh = 0; kh < 2; kh++)
          pa[ih][kh] = *(const short8*)&Ps[(wave * 32 + ih * 16 + l16) * 76 +
                                            kh * 32 + quad * 8];
#pragma unroll
      for (int tj = 0; tj < 4; tj++) {
        short8 b0 = *(const short8*)&Vt[cur][(tj * 16 + l16) * 64 + SWZ_RD(quad, l7)];
        short8 b1 = *(const short8*)&Vt[cur][(tj * 16 + l16) * 64 + SWZ_RD(4 + quad, l7)];
#pragma unroll
        for (int ih = 0; ih < 2; ih++) {
          O[ih][tj] = MFMA(pa[ih][0], b0, O[ih][tj]);
          O[ih][tj] = MFMA(pa[ih][1], b1, O[ih][tj]);
        }
      }
    }
    __syncthreads();   // compute-reads of buf[cur] done; prefetch drained
  }

#pragma unroll
  for (int ih = 0; ih < 2; ih++)
#pragma unroll
    for (int r = 0; r < 4; r++) {
      float lsum = l_[ih][r];
#pragma unroll
      for (int off = 1; off < 16; off <<= 1)
        lsum += __shfl_xor(lsum, off, 16);
      float inv = 1.0f / lsum;
      int t = qt * 128 + wave * 32 + ih * 16 + quad * 4 + r;
#pragma unroll
      for (int tj = 0; tj < 4; tj++) {
        int e = tj * 16 + l16;
        o[((size_t)(b * SEQ + t)) * DM + h * HS + e] = f2bf(O[ih][tj][r] * inv);
      }
    }
}

// ---------- G3: output projection, 128x128 tiles ----------
__global__ __launch_bounds__(256) void out_gemm128(
    const unsigned short* __restrict__ A,
    const unsigned short* __restrict__ Bt,
    const float* __restrict__ bo,
    float* __restrict__ out) {
  __shared__ __align__(16) short As[128 * 64];
  __shared__ __align__(16) short Bs[128 * 64];
  const int tid = threadIdx.x;
  const int bm = blockIdx.x, bn = blockIdx.y;
  const int lane = tid & 63, wave = tid >> 6;
  const int quad = lane >> 4, l16 = lane & 15;
  const int wr = wave >> 1, wc = wave & 1;
  const int l7 = l16 & 7;
  const floatx4 fzero = {0.f, 0.f, 0.f, 0.f};

  floatx4 acc[4][4];
#pragma unroll
  for (int i = 0; i < 4; i++)
#pragma unroll
    for (int j = 0; j < 4; j++) acc[i][j] = fzero;

  const int srow = tid >> 3;
  const int scolw = SWZ_SRC(tid);
  const unsigned short* Ag = A + (size_t)(bm * 128 + srow) * DM + scolw;
  const unsigned short* Bg = Bt + (size_t)(bn * 128 + srow) * DM + scolw;
  short* Ad = As + tid * 8;
  short* Bd = Bs + tid * 8;

  for (int k0 = 0; k0 < DM; k0 += 64) {
    __syncthreads();
#pragma unroll
    for (int i = 0; i < 4; i++) g2l(Ag + (size_t)i * 32 * DM + k0, Ad + i * 2048);
#pragma unroll
    for (int i = 0; i < 4; i++) g2l(Bg + (size_t)i * 32 * DM + k0, Bd + i * 2048);
    __syncthreads();

    short8 af[4][2], bf[4][2];
#pragma unroll
    for (int ti = 0; ti < 4; ti++)
#pragma unroll
      for (int kh = 0; kh < 2; kh++)
        af[ti][kh] = *(const short8*)&As[(wr * 64 + ti * 16 + l16) * 64 +
                                          SWZ_RD(kh * 4 + quad, l7)];
#pragma unroll
    for (int tj = 0; tj < 4; tj++)
#pragma unroll
      for (int kh = 0; kh < 2; kh++)
        bf[tj][kh] = *(const short8*)&Bs[(wc * 64 + tj * 16 + l16) * 64 +
                                          SWZ_RD(kh * 4 + quad, l7)];
#pragma unroll
    for (int ti = 0; ti < 4; ti++)
#pragma unroll
      for (int tj = 0; tj < 4; tj++) {
        acc[ti][tj] = MFMA(af[ti][0], bf[tj][0], acc[ti][tj]);
        acc[ti][tj] = MFMA(af[ti][1], bf[tj][1], acc[ti][tj]);
      }
  }

#pragma unroll
  for (int ti = 0; ti < 4; ti++)
#pragma unroll
    for (int tj = 0; tj < 4; tj++) {
      int n = bn * 128 + wc * 64 + tj * 16 + l16;
      float bias = bo[n];
#pragma unroll
      for (int r = 0; r < 4; r++) {
        int m = bm * 128 + wr * 64 + ti * 16 + quad * 4 + r;
        out[(size_t)m * DM + n] = acc[ti][tj][r] + bias;
      }
    }
}

extern "C" void kernel_launch(void* const* d_in, const int* in_sizes, int n_in,
                              void* d_out, int out_size, void* d_ws, size_t ws_size,
                              hipStream_t stream) {
  const float* x  = (const float*)d_in[0];
  const float* Wq = (const float*)d_in[1];
  const float* Wk = (const float*)d_in[2];
  const float* Wv = (const float*)d_in[3];
  const float* Wo = (const float*)d_in[4];
  const float* bo = (const float*)d_in[5];
  float* out = (float*)d_out;

  const size_t nx = (size_t)NB * SEQ * DM;          // 4M
  const size_t nw = (size_t)DM * DM;                // 1M
  unsigned short* xb  = (unsigned short*)d_ws;
  unsigned short* wtq = xb + nx;                    // wtq|wtk|wtv contiguous
  unsigned short* wtk = wtq + nw;
  unsigned short* wtv = wtk + nw;
  unsigned short* wot = wtv + nw;
  unsigned short* qws = wot + nw;
  unsigned short* kws = qws + nx;
  unsigned short* vws = kws + nx;
  unsigned short* aws = vws + nx;

  dim3 blk(256);
  cast_x<<<dim3(1024), blk, 0, stream>>>(x, xb);
  prep_w<<<dim3(256, 4), blk, 0, stream>>>(Wq, Wk, Wv, Wo, wtq, wtk, wtv, wot);
  qkv_gemm128<<<dim3(32, 24), blk, 0, stream>>>(xb, wtq, qws, kws, vws);
  attn_kernel<<<dim3(512), blk, 0, stream>>>(qws, kws, vws, aws);
  out_gemm128<<<dim3(32, 8), blk, 0, stream>>>(aws, wot, bo, out);
}

// Round 6
// 157.455 us; speedup vs baseline: 2.1178x; 1.1020x over previous
//
#include <hip/hip_runtime.h>
#include <math.h>

#define NB 4
#define SEQ 1024
#define DM 1024
#define NH 16
#define HS 64

typedef __attribute__((ext_vector_type(8))) short short8;
typedef __attribute__((ext_vector_type(4))) short short4v;
typedef __attribute__((ext_vector_type(4))) float floatx4;

#define MFMA(a, b, c) __builtin_amdgcn_mfma_f32_16x16x32_bf16((a), (b), (c), 0, 0, 0)

static __device__ __forceinline__ unsigned short f2bf(float f) {
  unsigned int u = __float_as_uint(f);
  u += 0x7FFFu + ((u >> 16) & 1u);   // RNE
  return (unsigned short)(u >> 16);
}

// 16B async global->LDS. LDS dest = wave-uniform base + lane*16.
static __device__ __forceinline__ void g2l(const unsigned short* g, short* l) {
  __builtin_amdgcn_global_load_lds(
      (const __attribute__((address_space(1))) void*)g,
      (__attribute__((address_space(3))) void*)l, 16, 0, 0);
}

// XOR swizzle: LDS 16B-block blk of row r holds global 16B-block (blk ^ (r&7)).
#define SWZ_SRC(tid) ((((tid) & 7) ^ (((tid) >> 3) & 7)) << 3)
#define SWZ_RD(B, r) ((((B) ^ ((r) & 7)) << 3))

// ---------- P: cast x + transpose/cast weights, one launch ----------
// y=0..2: Wq/Wk/Wv [NH][DM][HS] -> Wt [NH*HS][DM]; y=3: Wo -> Wot[n][k];
// y=4: cast x f32->bf16 (each block: 4096 float4).
__global__ __launch_bounds__(256) void prep_all(
    const float* __restrict__ x,
    const float* __restrict__ Wq, const float* __restrict__ Wk,
    const float* __restrict__ Wv, const float* __restrict__ Wo,
    unsigned short* __restrict__ xb,
    unsigned short* __restrict__ Wtq, unsigned short* __restrict__ Wtk,
    unsigned short* __restrict__ Wtv, unsigned short* __restrict__ Wot) {
  __shared__ __align__(16) short Ts[64 * 72];
  const int tid = threadIdx.x;
  const int mat = blockIdx.y;
  if (mat == 4) {
    int base = blockIdx.x * 4096;
#pragma unroll
    for (int i = 0; i < 16; i++) {
      int idx4 = base + tid + i * 256;
      float4 v = *(const float4*)(x + (size_t)idx4 * 4);
      short4v o;
      o[0] = (short)f2bf(v.x); o[1] = (short)f2bf(v.y);
      o[2] = (short)f2bf(v.z); o[3] = (short)f2bf(v.w);
      *(short4v*)(xb + (size_t)idx4 * 4) = o;
    }
    return;
  }
  const float* src;
  unsigned short* dst;
  int r0, c0;
  if (mat < 3) {
    src = (mat == 0) ? Wq : (mat == 1) ? Wk : Wv;
    dst = (mat == 0) ? Wtq : (mat == 1) ? Wtk : Wtv;
    int h = blockIdx.x >> 4;
    int d0 = (blockIdx.x & 15) * 64;
    src += (size_t)(h * DM + d0) * HS;
    dst += (size_t)(h * HS) * DM + d0;
    r0 = HS;  c0 = DM;
  } else {
    src = Wo; dst = Wot;
    int k0 = (blockIdx.x >> 4) * 64;
    int n0 = (blockIdx.x & 15) * 64;
    src += (size_t)k0 * DM + n0;
    dst += (size_t)n0 * DM + k0;
    r0 = DM;  c0 = DM;
  }
#pragma unroll
  for (int i = 0; i < 4; i++) {
    int p = tid + i * 256;
    int row = p >> 4, c4 = (p & 15) << 2;
    float4 v = *(const float4*)(src + (size_t)row * r0 + c4);
    Ts[(c4 + 0) * 72 + row] = (short)f2bf(v.x);
    Ts[(c4 + 1) * 72 + row] = (short)f2bf(v.y);
    Ts[(c4 + 2) * 72 + row] = (short)f2bf(v.z);
    Ts[(c4 + 3) * 72 + row] = (short)f2bf(v.w);
  }
  __syncthreads();
#pragma unroll
  for (int i = 0; i < 2; i++) {
    int p = tid + i * 256;
    int row = p >> 3, c8 = (p & 7) << 3;
    *(short8*)(dst + (size_t)row * c0 + c8) = *(const short8*)&Ts[row * 72 + c8];
  }
}

// ---------- G1: fused QKV as one 4096x3072x1024 GEMM, 128x128 tiles ----------
// launch_bounds(256,3): cap regs so 3 blocks/CU co-reside (grid 768 = 3/CU).
__global__ __launch_bounds__(256, 3) void qkv_gemm128(
    const unsigned short* __restrict__ xb,
    const unsigned short* __restrict__ Wcat,
    unsigned short* __restrict__ qo,
    unsigned short* __restrict__ ko,
    unsigned short* __restrict__ vo) {
  __shared__ __align__(16) short As[128 * 64];
  __shared__ __align__(16) short Bs[128 * 64];
  const int tid = threadIdx.x;
  const int bm = blockIdx.x, bn = blockIdx.y;
  const int lane = tid & 63, wave = tid >> 6;
  const int quad = lane >> 4, l16 = lane & 15;
  const int wr = wave >> 1, wc = wave & 1;
  const int l7 = l16 & 7;
  const floatx4 fzero = {0.f, 0.f, 0.f, 0.f};

  floatx4 acc[4][4];
#pragma unroll
  for (int i = 0; i < 4; i++)
#pragma unroll
    for (int j = 0; j < 4; j++) acc[i][j] = fzero;

  const int srow = tid >> 3;
  const int scolw = SWZ_SRC(tid);
  const unsigned short* Ag = xb + (size_t)(bm * 128 + srow) * DM + scolw;
  const unsigned short* Bg = Wcat + (size_t)(bn * 128 + srow) * DM + scolw;
  short* Ad = As + tid * 8;
  short* Bd = Bs + tid * 8;

  for (int k0 = 0; k0 < DM; k0 += 64) {
    __syncthreads();
#pragma unroll
    for (int i = 0; i < 4; i++) g2l(Ag + (size_t)i * 32 * DM + k0, Ad + i * 2048);
#pragma unroll
    for (int i = 0; i < 4; i++) g2l(Bg + (size_t)i * 32 * DM + k0, Bd + i * 2048);
    __syncthreads();

    short8 af[4][2], bf[4][2];
#pragma unroll
    for (int ti = 0; ti < 4; ti++)
#pragma unroll
      for (int kh = 0; kh < 2; kh++)
        af[ti][kh] = *(const short8*)&As[(wr * 64 + ti * 16 + l16) * 64 +
                                          SWZ_RD(kh * 4 + quad, l7)];
#pragma unroll
    for (int tj = 0; tj < 4; tj++)
#pragma unroll
      for (int kh = 0; kh < 2; kh++)
        bf[tj][kh] = *(const short8*)&Bs[(wc * 64 + tj * 16 + l16) * 64 +
                                          SWZ_RD(kh * 4 + quad, l7)];
#pragma unroll
    for (int ti = 0; ti < 4; ti++)
#pragma unroll
      for (int tj = 0; tj < 4; tj++) {
        acc[ti][tj] = MFMA(af[ti][0], bf[tj][0], acc[ti][tj]);
        acc[ti][tj] = MFMA(af[ti][1], bf[tj][1], acc[ti][tj]);
      }
  }

  const int mat = bn >> 3;
  const int mbase = bm * 128 + wr * 64 + quad * 4;
  const int nn0 = (bn & 7) * 128 + wc * 64;
  if (mat < 2) {
    unsigned short* dst = (mat == 0) ? qo : ko;
#pragma unroll
    for (int ti = 0; ti < 4; ti++)
#pragma unroll
      for (int tj = 0; tj < 4; tj++) {
        int ecol = nn0 + tj * 16 + l16;
        int h = ecol >> 6, e = ecol & 63;
#pragma unroll
        for (int r = 0; r < 4; r++) {
          int m = mbase + ti * 16 + r;
          int b = m >> 10, t = m & (SEQ - 1);
          dst[((size_t)(b * NH + h) * SEQ + t) * HS + e] = f2bf(acc[ti][tj][r]);
        }
      }
  } else {
#pragma unroll
    for (int ti = 0; ti < 4; ti++)
#pragma unroll
      for (int tj = 0; tj < 4; tj++) {
        int ecol = nn0 + tj * 16 + l16;
        int h = ecol >> 6, e = ecol & 63;
        int m0 = mbase + ti * 16;
        int b = m0 >> 10, t0 = m0 & (SEQ - 1);
        short4v pv;
#pragma unroll
        for (int r = 0; r < 4; r++) pv[r] = (short)f2bf(acc[ti][tj][r]);
        *(short4v*)&vo[((size_t)(b * NH + h) * HS + e) * SEQ + t0] = pv;
      }
  }
}

// ---------- G2: flash attention, fixed-max softmax, dbuf K/V ----------
__global__ __launch_bounds__(256) void attn_kernel(
    const unsigned short* __restrict__ q,   // [B,H,T,HS]
    const unsigned short* __restrict__ k,   // [B,H,T,HS]
    const unsigned short* __restrict__ v,   // [B,H,HS,T]
    unsigned short* __restrict__ o)         // [B,T,H*HS]
{
  __shared__ __align__(16) short Qs[128 * 64];
  __shared__ __align__(16) short Ks[2][64 * 64];
  __shared__ __align__(16) short Vt[2][64 * 64];
  __shared__ __align__(16) short Ps[128 * 76];
  const int tid = threadIdx.x;
  const int lid = (int)blockIdx.x;
  const int jj = lid & 3, half = lid >> 8, pp = (lid >> 2) & 63;
  const int qt = half ? jj : 7 - jj;
  const int h = pp & 15, b = pp >> 4;
  const int lane = tid & 63, wave = tid >> 6;
  const int quad = lane >> 4, l16 = lane & 15;
  const int l7 = l16 & 7;
  const size_t bh = (size_t)(b * NH + h) * SEQ * HS;
  const unsigned short* qp = q + bh + (size_t)qt * 128 * HS;
  const unsigned short* kbase = k + bh;
  const unsigned short* vbase = v + (size_t)(b * NH + h) * HS * SEQ;
  const floatx4 fzero = {0.f, 0.f, 0.f, 0.f};
  const float c2 = 0.125f * 1.44269504089f;   // scale * log2(e)
  const float C0 = 16.0f * 1.44269504089f;    // fixed softmax max
  const int srow = tid >> 3;
  const int scolw = SWZ_SRC(tid);

#pragma unroll
  for (int i = 0; i < 4; i++)
    g2l(qp + (size_t)(srow + i * 32) * HS + scolw, Qs + tid * 8 + i * 2048);
  {
    const unsigned short* kp = kbase;
#pragma unroll
    for (int i = 0; i < 2; i++)
      g2l(kp + (size_t)(srow + i * 32) * HS + scolw, &Ks[0][tid * 8 + i * 2048]);
#pragma unroll
    for (int i = 0; i < 2; i++)
      g2l(vbase + (size_t)(srow + i * 32) * SEQ + scolw, &Vt[0][tid * 8 + i * 2048]);
  }
  __syncthreads();
  short8 qa[2][2];
#pragma unroll
  for (int ih = 0; ih < 2; ih++)
#pragma unroll
    for (int kh = 0; kh < 2; kh++)
      qa[ih][kh] = *(const short8*)&Qs[(wave * 32 + ih * 16 + l16) * 64 +
                                        SWZ_RD(kh * 4 + quad, l7)];

  const int rowbase = qt * 128 + wave * 32;
  float l_[2][4];
  floatx4 O[2][4];
#pragma unroll
  for (int ih = 0; ih < 2; ih++)
#pragma unroll
    for (int r = 0; r < 4; r++) l_[ih][r] = 0.f;
#pragma unroll
  for (int ih = 0; ih < 2; ih++)
#pragma unroll
    for (int tj = 0; tj < 4; tj++) O[ih][tj] = fzero;

  const int ktmax = 2 * qt + 1;
  for (int kt = 0; kt <= ktmax; kt++) {
    const int cur = kt & 1;
    if (kt < ktmax) {
      const unsigned short* kp = kbase + (size_t)(kt + 1) * 64 * HS;
#pragma unroll
      for (int i = 0; i < 2; i++)
        g2l(kp + (size_t)(srow + i * 32) * HS + scolw,
            &Ks[1 - cur][tid * 8 + i * 2048]);
#pragma unroll
      for (int i = 0; i < 2; i++)
        g2l(vbase + (size_t)(srow + i * 32) * SEQ + (kt + 1) * 64 + scolw,
            &Vt[1 - cur][tid * 8 + i * 2048]);
    }

    if (kt * 64 <= rowbase + 31) {
      floatx4 S[2][4];
#pragma unroll
      for (int tj = 0; tj < 4; tj++) {
        short8 b0 = *(const short8*)&Ks[cur][(tj * 16 + l16) * 64 + SWZ_RD(quad, l7)];
        short8 b1 = *(const short8*)&Ks[cur][(tj * 16 + l16) * 64 + SWZ_RD(4 + quad, l7)];
#pragma unroll
        for (int ih = 0; ih < 2; ih++) {
          floatx4 s = fzero;
          s = MFMA(qa[ih][0], b0, s);
          s = MFMA(qa[ih][1], b1, s);
          S[ih][tj] = s;
        }
      }
      if (kt * 64 + 63 > rowbase) {
#pragma unroll
        for (int ih = 0; ih < 2; ih++)
#pragma unroll
          for (int tj = 0; tj < 4; tj++) {
            int col = kt * 64 + tj * 16 + l16;
#pragma unroll
            for (int r = 0; r < 4; r++) {
              int row = rowbase + ih * 16 + quad * 4 + r;
              if (col > row) S[ih][tj][r] = -INFINITY;
            }
          }
      }
#pragma unroll
      for (int ih = 0; ih < 2; ih++)
#pragma unroll
        for (int tj = 0; tj < 4; tj++)
#pragma unroll
          for (int r = 0; r < 4; r++) {
            float pv = __builtin_amdgcn_exp2f(S[ih][tj][r] * c2 - C0);
            S[ih][tj][r] = pv;
            l_[ih][r] += pv;
          }
#pragma unroll
      for (int ih = 0; ih < 2; ih++)
#pragma unroll
        for (int tj = 0; tj < 4; tj++)
#pragma unroll
          for (int r = 0; r < 4; r++)
            Ps[(wave * 32 + ih * 16 + quad * 4 + r) * 76 + tj * 16 + l16] =
                (short)f2bf(S[ih][tj][r]);

      short8 pa[2][2];
#pragma unroll
      for (int ih = 0; ih < 2; ih++)
#pragma unroll
        for (int kh = 0; kh < 2; kh++)
          pa[ih][kh] = *(const short8*)&Ps[(wave * 32 + ih * 16 + l16) * 76 +
                                            kh * 32 + quad * 8];
#pragma unroll
      for (int tj = 0; tj < 4; tj++) {
        short8 b0 = *(const short8*)&Vt[cur][(tj * 16 + l16) * 64 + SWZ_RD(quad, l7)];
        short8 b1 = *(const short8*)&Vt[cur][(tj * 16 + l16) * 64 + SWZ_RD(4 + quad, l7)];
#pragma unroll
        for (int ih = 0; ih < 2; ih++) {
          O[ih][tj] = MFMA(pa[ih][0], b0, O[ih][tj]);
          O[ih][tj] = MFMA(pa[ih][1], b1, O[ih][tj]);
        }
      }
    }
    __syncthreads();
  }

#pragma unroll
  for (int ih = 0; ih < 2; ih++)
#pragma unroll
    for (int r = 0; r < 4; r++) {
      float lsum = l_[ih][r];
#pragma unroll
      for (int off = 1; off < 16; off <<= 1)
        lsum += __shfl_xor(lsum, off, 16);
      float inv = 1.0f / lsum;
      int t = qt * 128 + wave * 32 + ih * 16 + quad * 4 + r;
#pragma unroll
      for (int tj = 0; tj < 4; tj++) {
        int e = tj * 16 + l16;
        o[((size_t)(b * SEQ + t)) * DM + h * HS + e] = f2bf(O[ih][tj][r] * inv);
      }
    }
}

// ---------- G3: output projection, 128x64 tiles (512 blocks = 2/CU) ----------
__global__ __launch_bounds__(256, 3) void out_gemm64(
    const unsigned short* __restrict__ A,    // [4096][1024] bf16
    const unsigned short* __restrict__ Bt,   // Wot [n][k]
    const float* __restrict__ bo,
    float* __restrict__ out) {
  __shared__ __align__(16) short As[128 * 64];
  __shared__ __align__(16) short Bs[64 * 64];
  const int tid = threadIdx.x;
  const int bm = blockIdx.x, bn = blockIdx.y;
  const int lane = tid & 63, wave = tid >> 6;
  const int quad = lane >> 4, l16 = lane & 15;
  const int wr = wave >> 1, wc = wave & 1;
  const int l7 = l16 & 7;
  const floatx4 fzero = {0.f, 0.f, 0.f, 0.f};

  floatx4 acc[4][2];
#pragma unroll
  for (int i = 0; i < 4; i++)
#pragma unroll
    for (int j = 0; j < 2; j++) acc[i][j] = fzero;

  const int srow = tid >> 3;
  const int scolw = SWZ_SRC(tid);
  const unsigned short* Ag = A + (size_t)(bm * 128 + srow) * DM + scolw;
  const unsigned short* Bg = Bt + (size_t)(bn * 64 + srow) * DM + scolw;
  short* Ad = As + tid * 8;
  short* Bd = Bs + tid * 8;

  for (int k0 = 0; k0 < DM; k0 += 64) {
    __syncthreads();
#pragma unroll
    for (int i = 0; i < 4; i++) g2l(Ag + (size_t)i * 32 * DM + k0, Ad + i * 2048);
#pragma unroll
    for (int i = 0; i < 2; i++) g2l(Bg + (size_t)i * 32 * DM + k0, Bd + i * 2048);
    __syncthreads();

    short8 af[4][2], bf[2][2];
#pragma unroll
    for (int ti = 0; ti < 4; ti++)
#pragma unroll
      for (int kh = 0; kh < 2; kh++)
        af[ti][kh] = *(const short8*)&As[(wr * 64 + ti * 16 + l16) * 64 +
                                          SWZ_RD(kh * 4 + quad, l7)];
#pragma unroll
    for (int tj = 0; tj < 2; tj++)
#pragma unroll
      for (int kh = 0; kh < 2; kh++)
        bf[tj][kh] = *(const short8*)&Bs[(wc * 32 + tj * 16 + l16) * 64 +
                                          SWZ_RD(kh * 4 + quad, l7)];
#pragma unroll
    for (int ti = 0; ti < 4; ti++)
#pragma unroll
      for (int tj = 0; tj < 2; tj++) {
        acc[ti][tj] = MFMA(af[ti][0], bf[tj][0], acc[ti][tj]);
        acc[ti][tj] = MFMA(af[ti][1], bf[tj][1], acc[ti][tj]);
      }
  }

#pragma unroll
  for (int ti = 0; ti < 4; ti++)
#pragma unroll
    for (int tj = 0; tj < 2; tj++) {
      int n = bn * 64 + wc * 32 + tj * 16 + l16;
      float bias = bo[n];
#pragma unroll
      for (int r = 0; r < 4; r++) {
        int m = bm * 128 + wr * 64 + ti * 16 + quad * 4 + r;
        out[(size_t)m * DM + n] = acc[ti][tj][r] + bias;
      }
    }
}

extern "C" void kernel_launch(void* const* d_in, const int* in_sizes, int n_in,
                              void* d_out, int out_size, void* d_ws, size_t ws_size,
                              hipStream_t stream) {
  const float* x  = (const float*)d_in[0];
  const float* Wq = (const float*)d_in[1];
  const float* Wk = (const float*)d_in[2];
  const float* Wv = (const float*)d_in[3];
  const float* Wo = (const float*)d_in[4];
  const float* bo = (const float*)d_in[5];
  float* out = (float*)d_out;

  const size_t nx = (size_t)NB * SEQ * DM;          // 4M
  const size_t nw = (size_t)DM * DM;                // 1M
  unsigned short* xb  = (unsigned short*)d_ws;
  unsigned short* wtq = xb + nx;                    // wtq|wtk|wtv contiguous
  unsigned short* wtk = wtq + nw;
  unsigned short* wtv = wtk + nw;
  unsigned short* wot = wtv + nw;
  unsigned short* qws = wot + nw;
  unsigned short* kws = qws + nx;
  unsigned short* vws = kws + nx;
  unsigned short* aws = vws + nx;

  dim3 blk(256);
  prep_all<<<dim3(256, 5), blk, 0, stream>>>(x, Wq, Wk, Wv, Wo,
                                             xb, wtq, wtk, wtv, wot);
  qkv_gemm128<<<dim3(32, 24), blk, 0, stream>>>(xb, wtq, qws, kws, vws);
  attn_kernel<<<dim3(512), blk, 0, stream>>>(qws, kws, vws, aws);
  out_gemm64<<<dim3(32, 16), blk, 0, stream>>>(aws, wot, bo, out);
}